// Round 4
// baseline (1008.750 us; speedup 1.0000x reference)
//
#include <hip/hip_runtime.h>
#include <hip/hip_bf16.h>
#include <math.h>

// Problem dims
#define BB  4
#define TT  1024
#define DD  1024
#define HH  16
#define DH  64
#define DFF 4096
#define MHH 256

typedef __attribute__((ext_vector_type(8))) short bf16x8;   // 8 bf16 = 4 VGPRs
typedef __attribute__((ext_vector_type(4))) float f32x4;

#define NEG_BIG (-1e9f)   // mask sentinel: exp underflows to 0, stays finite

__device__ __forceinline__ float b2f(short s) {
    union { unsigned int u; float f; } x;
    x.u = ((unsigned int)(unsigned short)s) << 16;
    return x.f;
}
__device__ __forceinline__ short f2b(float f) {
    union { float f; unsigned int u; } x; x.f = f;
    unsigned int r = x.u + 0x7fffu + ((x.u >> 16) & 1u);   // RNE
    return (short)(r >> 16);
}
__device__ __forceinline__ float silu_f(float x) { return x / (1.f + __expf(-x)); }

// ---------------------------------------------------------------- RMSNorm ---
// X: fp32 (XF32=true) or bf16 workspace (XF32=false). W fp32. O bf16.
template<bool XF32>
__global__ __launch_bounds__(256) void rmsnorm_k(
    const void* __restrict__ Xv, const float* __restrict__ W, short* __restrict__ O)
{
    const int row = blockIdx.x;           // B*T rows, D=1024 each
    const int tid = threadIdx.x;          // 256 threads * 4 elems
    float f0, f1, f2, f3;
    if (XF32) {
        float4 xv = ((const float4*)((const float*)Xv + (size_t)row * DD))[tid];
        f0 = xv.x; f1 = xv.y; f2 = xv.z; f3 = xv.w;
    } else {
        short4 xv = ((const short4*)((const short*)Xv + (size_t)row * DD))[tid];
        f0 = b2f(xv.x); f1 = b2f(xv.y); f2 = b2f(xv.z); f3 = b2f(xv.w);
    }
    float ss = f0*f0 + f1*f1 + f2*f2 + f3*f3;
    #pragma unroll
    for (int m = 1; m < 64; m <<= 1) ss += __shfl_xor(ss, m);
    __shared__ float red[4];
    if ((tid & 63) == 0) red[tid >> 6] = ss;
    __syncthreads();
    float tot = red[0] + red[1] + red[2] + red[3];
    float scale = rsqrtf(tot * (1.f / DD) + 1e-6f);
    float4 wv = ((const float4*)W)[tid];
    short4 ov;
    ov.x = f2b(f0 * scale * wv.x);
    ov.y = f2b(f1 * scale * wv.y);
    ov.z = f2b(f2 * scale * wv.z);
    ov.w = f2b(f3 * scale * wv.w);
    ((short4*)(O + (size_t)row * DD))[tid] = ov;
}

// ------------------------------------------------------------------- GEMM ---
// C[M,N] = A[M,K] @ B[K,N]. A bf16 (ws), B fp32 (input weights, converted
// during LDS staging), fp32 MFMA accum. C bf16 or fp32 (CF32). aux for
// EP_RES: fp32 (AUXF32) or bf16. 64x64 tile, BK=32.
#define EP_NONE     0
#define EP_SILU     1
#define EP_SOFTPLUS 2
#define EP_RES      3

template<int EP, bool CF32, bool AUXF32>
__global__ __launch_bounds__(256) void gemm_k(
    const short* __restrict__ A, const float* __restrict__ Bw,
    void* __restrict__ Cv, const void* __restrict__ auxv,
    int M, int N, int K)
{
    __shared__ __align__(16) short As[64][40];   // A tile [m][k], +8 pad
    __shared__ __align__(16) short Bs[64][40];   // B tile transposed: Bs[n][k]
    const int tid  = threadIdx.x;
    const int wave = tid >> 6, lane = tid & 63;
    const int l16  = lane & 15, quad = lane >> 4;
    const int m0 = blockIdx.y * 64, n0 = blockIdx.x * 64;

    const f32x4 z = {0.f, 0.f, 0.f, 0.f};
    f32x4 acc[4] = {z, z, z, z};

    const int ar = tid >> 2, ac = (tid & 3) * 8;   // A stage: 64 rows x 32 cols
    const int bk = tid >> 3, bn = (tid & 7) * 8;   // B stage: 32 rows x 64 cols

    for (int kb = 0; kb < K; kb += 32) {
        *(int4*)&As[ar][ac] = *(const int4*)(A + (size_t)(m0 + ar) * K + kb + ac);
        const float* bp = Bw + (size_t)(kb + bk) * N + n0 + bn;
        float4 b0 = *(const float4*)bp;
        float4 b1 = *(const float4*)(bp + 4);
        short bv[8] = { f2b(b0.x), f2b(b0.y), f2b(b0.z), f2b(b0.w),
                        f2b(b1.x), f2b(b1.y), f2b(b1.z), f2b(b1.w) };
        #pragma unroll
        for (int j = 0; j < 8; j++) Bs[bn + j][bk] = bv[j];
        __syncthreads();
        bf16x8 af = *(bf16x8*)&As[wave * 16 + l16][quad * 8];
        #pragma unroll
        for (int ns = 0; ns < 4; ns++) {
            bf16x8 bf = *(bf16x8*)&Bs[ns * 16 + l16][quad * 8];
            acc[ns] = __builtin_amdgcn_mfma_f32_16x16x32_bf16(af, bf, acc[ns], 0, 0, 0);
        }
        __syncthreads();
    }
    // C/D layout: row=(lane>>4)*4+reg, col=lane&15  [verified m89/m91]
    #pragma unroll
    for (int ns = 0; ns < 4; ns++) {
        #pragma unroll
        for (int r = 0; r < 4; r++) {
            int row = m0 + wave * 16 + quad * 4 + r;
            int col = n0 + ns * 16 + l16;
            size_t idx = (size_t)row * N + col;
            float v = acc[ns][r];
            if (EP == EP_SILU)          v = silu_f(v);
            else if (EP == EP_SOFTPLUS) v = fmaxf(v, 0.f) + log1pf(__expf(-fabsf(v)));
            else if (EP == EP_RES) {
                if (AUXF32) v += ((const float*)auxv)[idx];
                else        v += b2f(((const short*)auxv)[idx]);
            }
            if (CF32) ((float*)Cv)[idx] = v;
            else      ((short*)Cv)[idx] = f2b(v);
        }
    }
}

// ------------------------------------------ fused SwiGLU GEMM (gate & up) ---
// F[M,N] = silu(A@Gw) * (A@Uw), one pass over A. Gw/Uw fp32, F bf16.
__global__ __launch_bounds__(256) void gemm_swiglu_k(
    const short* __restrict__ A, const float* __restrict__ Gw,
    const float* __restrict__ Uw, short* __restrict__ F,
    int M, int N, int K)
{
    __shared__ __align__(16) short As[64][40];
    __shared__ __align__(16) short Bg[64][40];
    __shared__ __align__(16) short Bu[64][40];
    const int tid  = threadIdx.x;
    const int wave = tid >> 6, lane = tid & 63;
    const int l16  = lane & 15, quad = lane >> 4;
    const int m0 = blockIdx.y * 64, n0 = blockIdx.x * 64;

    const f32x4 z = {0.f, 0.f, 0.f, 0.f};
    f32x4 ag[4] = {z, z, z, z};
    f32x4 au[4] = {z, z, z, z};

    const int ar = tid >> 2, ac = (tid & 3) * 8;
    const int bk = tid >> 3, bn = (tid & 7) * 8;

    for (int kb = 0; kb < K; kb += 32) {
        *(int4*)&As[ar][ac] = *(const int4*)(A + (size_t)(m0 + ar) * K + kb + ac);
        size_t boff = (size_t)(kb + bk) * N + n0 + bn;
        float4 g0 = *(const float4*)(Gw + boff);
        float4 g1 = *(const float4*)(Gw + boff + 4);
        float4 u0 = *(const float4*)(Uw + boff);
        float4 u1 = *(const float4*)(Uw + boff + 4);
        short gv[8] = { f2b(g0.x), f2b(g0.y), f2b(g0.z), f2b(g0.w),
                        f2b(g1.x), f2b(g1.y), f2b(g1.z), f2b(g1.w) };
        short uv[8] = { f2b(u0.x), f2b(u0.y), f2b(u0.z), f2b(u0.w),
                        f2b(u1.x), f2b(u1.y), f2b(u1.z), f2b(u1.w) };
        #pragma unroll
        for (int j = 0; j < 8; j++) { Bg[bn + j][bk] = gv[j]; Bu[bn + j][bk] = uv[j]; }
        __syncthreads();
        bf16x8 af = *(bf16x8*)&As[wave * 16 + l16][quad * 8];
        #pragma unroll
        for (int ns = 0; ns < 4; ns++) {
            bf16x8 bg = *(bf16x8*)&Bg[ns * 16 + l16][quad * 8];
            bf16x8 bu = *(bf16x8*)&Bu[ns * 16 + l16][quad * 8];
            ag[ns] = __builtin_amdgcn_mfma_f32_16x16x32_bf16(af, bg, ag[ns], 0, 0, 0);
            au[ns] = __builtin_amdgcn_mfma_f32_16x16x32_bf16(af, bu, au[ns], 0, 0, 0);
        }
        __syncthreads();
    }
    #pragma unroll
    for (int ns = 0; ns < 4; ns++) {
        #pragma unroll
        for (int r = 0; r < 4; r++) {
            int row = m0 + wave * 16 + quad * 4 + r;
            int col = n0 + ns * 16 + l16;
            F[(size_t)row * N + col] = f2b(silu_f(ag[ns][r]) * au[ns][r]);
        }
    }
}

// ------------------------------------- gk = g*k in-place, c = sum gk*k ------
__global__ __launch_bounds__(256) void gkc_k(
    const short* __restrict__ G, short* KG,   // KG: reads k, writes g*k
    float* __restrict__ Cj)
{
    const int bt  = blockIdx.x;            // b*T + t
    const int tid = threadIdx.x;           // 16 lanes per head, 4 elems each
    const int h = tid >> 4, d0 = (tid & 15) * 4;
    const size_t base = (size_t)bt * (HH * DH) + h * DH + d0;
    short4 gv = *(const short4*)(G + base);
    short4 kv = *(const short4*)(KG + base);
    float g0 = b2f(gv.x), g1 = b2f(gv.y), g2 = b2f(gv.z), g3 = b2f(gv.w);
    float k0 = b2f(kv.x), k1 = b2f(kv.y), k2 = b2f(kv.z), k3 = b2f(kv.w);
    float p0 = g0*k0, p1 = g1*k1, p2 = g2*k2, p3 = g3*k3;
    short4 ov; ov.x = f2b(p0); ov.y = f2b(p1); ov.z = f2b(p2); ov.w = f2b(p3);
    *(short4*)(KG + base) = ov;
    float cc = p0*k0 + p1*k1 + p2*k2 + p3*k3;
    #pragma unroll
    for (int m = 1; m < 16; m <<= 1) cc += __shfl_xor(cc, m);
    if ((tid & 15) == 0) {
        int b = bt >> 10, t = bt & (TT - 1);
        Cj[((size_t)b * HH + h) * TT + t] = cc;
    }
}

// -------------------------------------------------- flash geodesic attention -
// scores = (2*q.gk^T - qq.g^T - c_j) / 8, causal, online softmax, O = P.V
__global__ __launch_bounds__(256) void attn_k(
    const short* __restrict__ Q, const short* __restrict__ G,
    const short* __restrict__ GK, const short* __restrict__ V,
    const float* __restrict__ Cj, short* __restrict__ O)
{
    __shared__ __align__(16) short Gs[32][72];    // [j][d] +8 pad
    __shared__ __align__(16) short GKs[32][72];
    __shared__ __align__(16) short Vt[64][40];    // transposed: [d][j]
    __shared__ __align__(16) float Cs[32];
    __shared__ __align__(16) short Ps[4][16][40]; // per-wave P (16x32) C->A

    const int it = blockIdx.x, bh = blockIdx.y;
    const int b = bh >> 4, h = bh & 15;
    const int i0 = it * 64;
    const int tid  = threadIdx.x;
    const int wave = tid >> 6, lane = tid & 63;
    const int l16  = lane & 15, quad = lane >> 4;

    const size_t bh_base = ((size_t)b * TT) * (HH * DH) + (size_t)h * DH;

    const int qrow = i0 + wave * 16 + l16;
    bf16x8 qf[2], qqf[2];
    #pragma unroll
    for (int kc = 0; kc < 2; kc++) {
        qf[kc] = *(const bf16x8*)(Q + bh_base + (size_t)qrow * (HH * DH) + kc * 32 + quad * 8);
        #pragma unroll
        for (int j = 0; j < 8; j++) {
            float f = b2f(qf[kc][j]);
            qqf[kc][j] = f2b(f * f);
        }
    }

    float m_i[4], l_i[4];
    const f32x4 z = {0.f, 0.f, 0.f, 0.f};
    f32x4 o_acc[4] = {z, z, z, z};
    #pragma unroll
    for (int r = 0; r < 4; r++) { m_i[r] = NEG_BIG; l_i[r] = 0.f; }

    const int sr = tid >> 3, sc = (tid & 7) * 8;   // staging: 32 rows x 64 cols
    const int jt_max = (i0 + 63) >> 5;
    for (int jt = 0; jt <= jt_max; jt++) {
        const int j0 = jt * 32;
        {
            size_t rb = bh_base + (size_t)(j0 + sr) * (HH * DH) + sc;
            *(int4*)&Gs[sr][sc]  = *(const int4*)(G + rb);
            *(int4*)&GKs[sr][sc] = *(const int4*)(GK + rb);
            int4 vvec = *(const int4*)(V + rb);
            const short* vv = (const short*)&vvec;
            #pragma unroll
            for (int j = 0; j < 8; j++) Vt[sc + j][sr] = vv[j];
            if (tid < 32) Cs[tid] = Cj[((size_t)b * HH + h) * TT + j0 + tid];
        }
        __syncthreads();

        f32x4 s1[2] = {z, z}, s2[2] = {z, z};
        #pragma unroll
        for (int ns = 0; ns < 2; ns++) {
            #pragma unroll
            for (int kc = 0; kc < 2; kc++) {
                bf16x8 gf  = *(bf16x8*)&Gs [ns * 16 + l16][kc * 32 + quad * 8];
                bf16x8 gkf = *(bf16x8*)&GKs[ns * 16 + l16][kc * 32 + quad * 8];
                s1[ns] = __builtin_amdgcn_mfma_f32_16x16x32_bf16(qqf[kc], gf,  s1[ns], 0, 0, 0);
                s2[ns] = __builtin_amdgcn_mfma_f32_16x16x32_bf16(qf[kc],  gkf, s2[ns], 0, 0, 0);
            }
        }

        float p[2][4];
        float cj0 = Cs[l16], cj1 = Cs[16 + l16];
        #pragma unroll
        for (int ns = 0; ns < 2; ns++) {
            int j = j0 + ns * 16 + l16;
            float cjv = ns ? cj1 : cj0;
            #pragma unroll
            for (int r = 0; r < 4; r++) {
                int i = i0 + wave * 16 + quad * 4 + r;
                float s = (2.f * s2[ns][r] - s1[ns][r] - cjv) * 0.125f;
                p[ns][r] = (j > i) ? NEG_BIG : s;
            }
        }
        #pragma unroll
        for (int r = 0; r < 4; r++) {
            float mx = fmaxf(p[0][r], p[1][r]);
            #pragma unroll
            for (int d2 = 1; d2 < 16; d2 <<= 1) mx = fmaxf(mx, __shfl_xor(mx, d2));
            float mnew = fmaxf(m_i[r], mx);
            float corr = __expf(m_i[r] - mnew);
            float p0v = __expf(p[0][r] - mnew);
            float p1v = __expf(p[1][r] - mnew);
            p[0][r] = p0v; p[1][r] = p1v;
            float sp = p0v + p1v;
            #pragma unroll
            for (int d2 = 1; d2 < 16; d2 <<= 1) sp += __shfl_xor(sp, d2);
            l_i[r] = l_i[r] * corr + sp;
            m_i[r] = mnew;
            #pragma unroll
            for (int nv = 0; nv < 4; nv++) o_acc[nv][r] *= corr;
        }
        #pragma unroll
        for (int ns = 0; ns < 2; ns++)
            #pragma unroll
            for (int r = 0; r < 4; r++)
                Ps[wave][quad * 4 + r][ns * 16 + l16] = f2b(p[ns][r]);
        __syncthreads();

        bf16x8 pf = *(bf16x8*)&Ps[wave][l16][quad * 8];
        #pragma unroll
        for (int nv = 0; nv < 4; nv++) {
            bf16x8 vf = *(bf16x8*)&Vt[nv * 16 + l16][quad * 8];
            o_acc[nv] = __builtin_amdgcn_mfma_f32_16x16x32_bf16(pf, vf, o_acc[nv], 0, 0, 0);
        }
        __syncthreads();
    }

    #pragma unroll
    for (int nv = 0; nv < 4; nv++) {
        #pragma unroll
        for (int r = 0; r < 4; r++) {
            int i = i0 + wave * 16 + quad * 4 + r;
            int d = nv * 16 + l16;
            O[bh_base + (size_t)i * (HH * DH) + d] = f2b(o_acc[nv][r] / l_i[r]);
        }
    }
}

// ------------------------------------------------------------------ launch ---
extern "C" void kernel_launch(void* const* d_in, const int* in_sizes, int n_in,
                              void* d_out, int out_size, void* d_ws, size_t ws_size,
                              hipStream_t stream)
{
    // Inputs are float32 per the reference's setup_inputs.
    const float* x   = (const float*)d_in[0];
    const float* n1w = (const float*)d_in[1];
    const float* n2w = (const float*)d_in[2];
    const float* wq  = (const float*)d_in[3];
    const float* wk  = (const float*)d_in[4];
    const float* wv  = (const float*)d_in[5];
    const float* wo  = (const float*)d_in[6];
    const float* mw1 = (const float*)d_in[7];
    const float* mw2 = (const float*)d_in[8];
    const float* gw  = (const float*)d_in[9];
    const float* uw  = (const float*)d_in[10];
    const float* dw  = (const float*)d_in[11];
    float* out = (float*)d_out;   // float32 output per reference

    // Workspace: 48 MB bf16 intermediates, lifetime-aliased (L1..L12):
    //   S0: h(L1-5) -> ob(L8-9) -> ffn[0:8M](L11-12)
    //   S1: kb(L3-7, gk in-place L7-8) -> ffn[8:16M]
    //   S2: g(L6-8) -> ffn[16:24M]
    //   S3: vb(L4-8) -> ffn[24:32M]
    //   S4: qb(L2-8) -> x2 bf16(L9-12)
    //   S5: m1(L5-6) + cj@+2MB(L7-8) -> h2(L10-11)
    const size_t SZ8 = (size_t)BB * TT * DD * 2;        // 8 MB
    const size_t NEED = 6 * SZ8;
    if (ws_size < NEED) return;   // diagnostic: absmax==5.375 => ws too small
    char* ws = (char*)d_ws;
    short* h    = (short*)(ws);            short* ob = (short*)(ws);
    short* kb   = (short*)(ws + SZ8);
    short* g    = (short*)(ws + 2*SZ8);
    short* vb   = (short*)(ws + 3*SZ8);
    short* ffn  = (short*)(ws);
    short* qb   = (short*)(ws + 4*SZ8);    short* x2 = (short*)(ws + 4*SZ8);
    short* m1   = (short*)(ws + 5*SZ8);    short* h2 = (short*)(ws + 5*SZ8);
    float* cj   = (float*)(ws + 5*SZ8 + (2<<20));

    const int M = BB * TT;  // 4096 token rows

    rmsnorm_k<true>  <<<M, 256, 0, stream>>>(x, n1w, h);                                       // L1
    gemm_k<EP_NONE,false,true>    <<<dim3(DD /64, M/64), 256, 0, stream>>>(h,  wq,  qb, nullptr, M, DD,  DD);  // L2
    gemm_k<EP_NONE,false,true>    <<<dim3(DD /64, M/64), 256, 0, stream>>>(h,  wk,  kb, nullptr, M, DD,  DD);  // L3
    gemm_k<EP_NONE,false,true>    <<<dim3(DD /64, M/64), 256, 0, stream>>>(h,  wv,  vb, nullptr, M, DD,  DD);  // L4
    gemm_k<EP_SILU,false,true>    <<<dim3(MHH/64, M/64), 256, 0, stream>>>(h,  mw1, m1, nullptr, M, MHH, DD);  // L5
    gemm_k<EP_SOFTPLUS,false,true><<<dim3(DD /64, M/64), 256, 0, stream>>>(m1, mw2, g,  nullptr, M, DD,  MHH); // L6
    gkc_k<<<M, 256, 0, stream>>>(g, kb, cj);                                                   // L7
    attn_k<<<dim3(TT/64, BB*HH), 256, 0, stream>>>(qb, g, kb, vb, cj, ob);                     // L8
    gemm_k<EP_RES,false,true>     <<<dim3(DD /64, M/64), 256, 0, stream>>>(ob, wo,  x2, x,       M, DD,  DD);  // L9
    rmsnorm_k<false> <<<M, 256, 0, stream>>>(x2, n2w, h2);                                     // L10
    gemm_swiglu_k                 <<<dim3(DFF/64, M/64), 256, 0, stream>>>(h2, gw, uw, ffn,      M, DFF, DD);  // L11
    gemm_k<EP_RES,true,false>     <<<dim3(DD /64, M/64), 256, 0, stream>>>(ffn, dw, out, x2,     M, DD,  DFF); // L12
}

// Round 5
// 753.645 us; speedup vs baseline: 1.3385x; 1.3385x over previous
//
#include <hip/hip_runtime.h>
#include <hip/hip_bf16.h>
#include <math.h>

// Problem dims
#define BB  4
#define TT  1024
#define DD  1024
#define HH  16
#define DH  64
#define DFF 4096
#define MHH 256

typedef __attribute__((ext_vector_type(8))) short bf16x8;   // 8 bf16 = 4 VGPRs
typedef __attribute__((ext_vector_type(4))) float f32x4;
typedef unsigned int u32;

#define NEG_BIG (-1e9f)   // mask sentinel: exp underflows to 0, stays finite

__device__ __forceinline__ float b2f(short s) {
    union { unsigned int u; float f; } x;
    x.u = ((unsigned int)(unsigned short)s) << 16;
    return x.f;
}
__device__ __forceinline__ short f2b(float f) {
    union { float f; unsigned int u; } x; x.f = f;
    unsigned int r = x.u + 0x7fffu + ((x.u >> 16) & 1u);   // RNE
    return (short)(r >> 16);
}
__device__ __forceinline__ float silu_f(float x) { return x / (1.f + __expf(-x)); }

// async global->LDS, 16B per lane. LDS dest must be wave_base + lane*16.
__device__ __forceinline__ void gld16(const short* g, short* l) {
    __builtin_amdgcn_global_load_lds(
        (const __attribute__((address_space(1))) u32*)g,
        (__attribute__((address_space(3))) u32*)l, 16, 0, 0);
}

// ------------------------------------------- weight fp32 [K,N] -> bf16 [N,K]
__global__ __launch_bounds__(256) void convT_k(
    const float* __restrict__ W, short* __restrict__ Wt, int K, int N)
{
    __shared__ __align__(16) short Ts[32][36];
    const int k0 = blockIdx.y * 32, n0 = blockIdx.x * 32;
    const int r = threadIdx.x >> 3, c4 = (threadIdx.x & 7) * 4;
    float4 v = *(const float4*)(W + (size_t)(k0 + r) * N + n0 + c4);
    Ts[r][c4 + 0] = f2b(v.x); Ts[r][c4 + 1] = f2b(v.y);
    Ts[r][c4 + 2] = f2b(v.z); Ts[r][c4 + 3] = f2b(v.w);
    __syncthreads();
    short4 o;
    o.x = Ts[c4 + 0][r]; o.y = Ts[c4 + 1][r];
    o.z = Ts[c4 + 2][r]; o.w = Ts[c4 + 3][r];
    *(short4*)(Wt + (size_t)(n0 + r) * K + k0 + c4) = o;
}

// ---------------------------------------------------------------- RMSNorm ---
__global__ __launch_bounds__(256) void rmsnorm_k(
    const float* __restrict__ X, const float* __restrict__ W, short* __restrict__ O)
{
    const int row = blockIdx.x;           // B*T rows, D=1024 each
    const int tid = threadIdx.x;          // 256 threads * 4 elems
    float4 xv = ((const float4*)(X + (size_t)row * DD))[tid];
    float f0 = xv.x, f1 = xv.y, f2 = xv.z, f3 = xv.w;
    float ss = f0*f0 + f1*f1 + f2*f2 + f3*f3;
    #pragma unroll
    for (int m = 1; m < 64; m <<= 1) ss += __shfl_xor(ss, m);
    __shared__ float red[4];
    if ((tid & 63) == 0) red[tid >> 6] = ss;
    __syncthreads();
    float tot = red[0] + red[1] + red[2] + red[3];
    float scale = rsqrtf(tot * (1.f / DD) + 1e-6f);
    float4 wv = ((const float4*)W)[tid];
    short4 ov;
    ov.x = f2b(f0 * scale * wv.x);
    ov.y = f2b(f1 * scale * wv.y);
    ov.z = f2b(f2 * scale * wv.z);
    ov.w = f2b(f3 * scale * wv.w);
    ((short4*)(O + (size_t)row * DD))[tid] = ov;
}

// ------------------------------------------------------- 128x128 MFMA GEMM --
// C[M,N] = A[M,K] @ Bt[N,K]^T. m97 structure: BK=32, global_load_lds dwordx4
// staging, 16 MFMA/wave/K-step, 4 waves in 2x2 of 64x64.
#define EP_NONE     0
#define EP_SILU     1
#define EP_SOFTPLUS 2
#define EP_RES      3

template<int EP, bool CF32, bool AUXF32>
__global__ __launch_bounds__(256) void gemm128_k(
    const short* __restrict__ A, const short* __restrict__ Bt,
    void* Cv, const void* auxv,
    int N, int K, int ldb)            // lda = K, ldc = N
{
    __shared__ __align__(16) short As[128 * 32];   // [m][k], no pad (gld16 constraint)
    __shared__ __align__(16) short Bs[128 * 32];   // [n][k]
    const int tid  = threadIdx.x;
    const int wave = tid >> 6, lane = tid & 63;
    const int l16  = lane & 15, quad = lane >> 4;
    const int m0 = blockIdx.y * 128, n0 = blockIdx.x * 128;
    const int wm = (wave & 1) * 64, wn = (wave >> 1) * 64;

    f32x4 acc[4][4];
    #pragma unroll
    for (int i = 0; i < 4; i++)
        #pragma unroll
        for (int j = 0; j < 4; j++) acc[i][j] = (f32x4){0.f, 0.f, 0.f, 0.f};

    const int srow = tid >> 2, scol = (tid & 3) * 8;   // 64 rows x 32 cols per issue
    const short* ga0 = A  + (size_t)(m0 + srow)      * K   + scol;
    const short* ga1 = A  + (size_t)(m0 + 64 + srow) * K   + scol;
    const short* gb0 = Bt + (size_t)(n0 + srow)      * ldb + scol;
    const short* gb1 = Bt + (size_t)(n0 + 64 + srow) * ldb + scol;
    short* la0 = &As[tid * 8];             // == [srow][scol]
    short* la1 = &As[64 * 32 + tid * 8];
    short* lb0 = &Bs[tid * 8];
    short* lb1 = &Bs[64 * 32 + tid * 8];

    for (int kb = 0; kb < K; kb += 32) {
        gld16(ga0 + kb, la0);
        gld16(ga1 + kb, la1);
        gld16(gb0 + kb, lb0);
        gld16(gb1 + kb, lb1);
        __syncthreads();                   // drains vmcnt before LDS reads
        bf16x8 af[4], bf[4];
        #pragma unroll
        for (int mi = 0; mi < 4; mi++)
            af[mi] = *(bf16x8*)&As[(wm + mi * 16 + l16) * 32 + quad * 8];
        #pragma unroll
        for (int ni = 0; ni < 4; ni++)
            bf[ni] = *(bf16x8*)&Bs[(wn + ni * 16 + l16) * 32 + quad * 8];
        #pragma unroll
        for (int mi = 0; mi < 4; mi++)
            #pragma unroll
            for (int ni = 0; ni < 4; ni++)
                acc[mi][ni] = __builtin_amdgcn_mfma_f32_16x16x32_bf16(af[mi], bf[ni], acc[mi][ni], 0, 0, 0);
        __syncthreads();
    }
    // C/D layout: row=(lane>>4)*4+reg, col=lane&15  [verified m89/m91]
    #pragma unroll
    for (int mi = 0; mi < 4; mi++) {
        #pragma unroll
        for (int ni = 0; ni < 4; ni++) {
            #pragma unroll
            for (int r = 0; r < 4; r++) {
                int row = m0 + wm + mi * 16 + quad * 4 + r;
                int col = n0 + wn + ni * 16 + l16;
                size_t idx = (size_t)row * N + col;
                float v = acc[mi][ni][r];
                if (EP == EP_SILU)          v = silu_f(v);
                else if (EP == EP_SOFTPLUS) v = fmaxf(v, 0.f) + log1pf(__expf(-fabsf(v)));
                else if (EP == EP_RES) {
                    if (AUXF32) v += ((const float*)auxv)[idx];
                    else        v += b2f(((const short*)auxv)[idx]);
                }
                if (CF32) ((float*)Cv)[idx] = v;
                else      ((short*)Cv)[idx] = f2b(v);
            }
        }
    }
}

// ----------------------------------- 128x128 fused SwiGLU (gate & up) GEMM --
__global__ __launch_bounds__(256) void gemm128_swiglu_k(
    const short* __restrict__ A, const short* __restrict__ Gt,
    const short* __restrict__ Ut, short* __restrict__ F,
    int N, int K, int ldb)
{
    __shared__ __align__(16) short As[128 * 32];
    __shared__ __align__(16) short Gs[128 * 32];
    __shared__ __align__(16) short Us[128 * 32];
    const int tid  = threadIdx.x;
    const int wave = tid >> 6, lane = tid & 63;
    const int l16  = lane & 15, quad = lane >> 4;
    const int m0 = blockIdx.y * 128, n0 = blockIdx.x * 128;
    const int wm = (wave & 1) * 64, wn = (wave >> 1) * 64;

    f32x4 ag[4][4], au[4][4];
    #pragma unroll
    for (int i = 0; i < 4; i++)
        #pragma unroll
        for (int j = 0; j < 4; j++) {
            ag[i][j] = (f32x4){0.f, 0.f, 0.f, 0.f};
            au[i][j] = (f32x4){0.f, 0.f, 0.f, 0.f};
        }

    const int srow = tid >> 2, scol = (tid & 3) * 8;
    const short* ga0 = A  + (size_t)(m0 + srow)      * K   + scol;
    const short* ga1 = A  + (size_t)(m0 + 64 + srow) * K   + scol;
    const short* gg0 = Gt + (size_t)(n0 + srow)      * ldb + scol;
    const short* gg1 = Gt + (size_t)(n0 + 64 + srow) * ldb + scol;
    const short* gu0 = Ut + (size_t)(n0 + srow)      * ldb + scol;
    const short* gu1 = Ut + (size_t)(n0 + 64 + srow) * ldb + scol;
    short* la0 = &As[tid * 8];
    short* la1 = &As[64 * 32 + tid * 8];
    short* lg0 = &Gs[tid * 8];
    short* lg1 = &Gs[64 * 32 + tid * 8];
    short* lu0 = &Us[tid * 8];
    short* lu1 = &Us[64 * 32 + tid * 8];

    for (int kb = 0; kb < K; kb += 32) {
        gld16(ga0 + kb, la0);
        gld16(ga1 + kb, la1);
        gld16(gg0 + kb, lg0);
        gld16(gg1 + kb, lg1);
        gld16(gu0 + kb, lu0);
        gld16(gu1 + kb, lu1);
        __syncthreads();
        bf16x8 af[4], gf[4], uf[4];
        #pragma unroll
        for (int mi = 0; mi < 4; mi++)
            af[mi] = *(bf16x8*)&As[(wm + mi * 16 + l16) * 32 + quad * 8];
        #pragma unroll
        for (int ni = 0; ni < 4; ni++) {
            gf[ni] = *(bf16x8*)&Gs[(wn + ni * 16 + l16) * 32 + quad * 8];
            uf[ni] = *(bf16x8*)&Us[(wn + ni * 16 + l16) * 32 + quad * 8];
        }
        #pragma unroll
        for (int mi = 0; mi < 4; mi++)
            #pragma unroll
            for (int ni = 0; ni < 4; ni++) {
                ag[mi][ni] = __builtin_amdgcn_mfma_f32_16x16x32_bf16(af[mi], gf[ni], ag[mi][ni], 0, 0, 0);
                au[mi][ni] = __builtin_amdgcn_mfma_f32_16x16x32_bf16(af[mi], uf[ni], au[mi][ni], 0, 0, 0);
            }
        __syncthreads();
    }
    #pragma unroll
    for (int mi = 0; mi < 4; mi++)
        #pragma unroll
        for (int ni = 0; ni < 4; ni++)
            #pragma unroll
            for (int r = 0; r < 4; r++) {
                int row = m0 + wm + mi * 16 + quad * 4 + r;
                int col = n0 + wn + ni * 16 + l16;
                F[(size_t)row * N + col] = f2b(silu_f(ag[mi][ni][r]) * au[mi][ni][r]);
            }
}

// ------------------------------------- gk = g*k in-place, c = sum gk*k ------
__global__ __launch_bounds__(256) void gkc_k(
    const short* __restrict__ G, short* KG,
    float* __restrict__ Cj)
{
    const int bt  = blockIdx.x;
    const int tid = threadIdx.x;
    const int h = tid >> 4, d0 = (tid & 15) * 4;
    const size_t base = (size_t)bt * (HH * DH) + h * DH + d0;
    short4 gv = *(const short4*)(G + base);
    short4 kv = *(const short4*)(KG + base);
    float g0 = b2f(gv.x), g1 = b2f(gv.y), g2 = b2f(gv.z), g3 = b2f(gv.w);
    float k0 = b2f(kv.x), k1 = b2f(kv.y), k2 = b2f(kv.z), k3 = b2f(kv.w);
    float p0 = g0*k0, p1 = g1*k1, p2 = g2*k2, p3 = g3*k3;
    short4 ov; ov.x = f2b(p0); ov.y = f2b(p1); ov.z = f2b(p2); ov.w = f2b(p3);
    *(short4*)(KG + base) = ov;
    float cc = p0*k0 + p1*k1 + p2*k2 + p3*k3;
    #pragma unroll
    for (int m = 1; m < 16; m <<= 1) cc += __shfl_xor(cc, m);
    if ((tid & 15) == 0) {
        int b = bt >> 10, t = bt & (TT - 1);
        Cj[((size_t)b * HH + h) * TT + t] = cc;
    }
}

// -------------------------------------------------- flash geodesic attention -
__global__ __launch_bounds__(256) void attn_k(
    const short* __restrict__ Q, const short* __restrict__ G,
    const short* __restrict__ GK, const short* __restrict__ V,
    const float* __restrict__ Cj, short* __restrict__ O)
{
    __shared__ __align__(16) short Gs[32][72];
    __shared__ __align__(16) short GKs[32][72];
    __shared__ __align__(16) short Vt[64][40];
    __shared__ __align__(16) float Cs[32];
    __shared__ __align__(16) short Ps[4][16][40];

    const int it = blockIdx.x, bh = blockIdx.y;
    const int b = bh >> 4, h = bh & 15;
    const int i0 = it * 64;
    const int tid  = threadIdx.x;
    const int wave = tid >> 6, lane = tid & 63;
    const int l16  = lane & 15, quad = lane >> 4;

    const size_t bh_base = ((size_t)b * TT) * (HH * DH) + (size_t)h * DH;

    const int qrow = i0 + wave * 16 + l16;
    bf16x8 qf[2], qqf[2];
    #pragma unroll
    for (int kc = 0; kc < 2; kc++) {
        qf[kc] = *(const bf16x8*)(Q + bh_base + (size_t)qrow * (HH * DH) + kc * 32 + quad * 8);
        #pragma unroll
        for (int j = 0; j < 8; j++) {
            float f = b2f(qf[kc][j]);
            qqf[kc][j] = f2b(f * f);
        }
    }

    float m_i[4], l_i[4];
    const f32x4 z = {0.f, 0.f, 0.f, 0.f};
    f32x4 o_acc[4] = {z, z, z, z};
    #pragma unroll
    for (int r = 0; r < 4; r++) { m_i[r] = NEG_BIG; l_i[r] = 0.f; }

    const int sr = tid >> 3, sc = (tid & 7) * 8;
    const int jt_max = (i0 + 63) >> 5;
    for (int jt = 0; jt <= jt_max; jt++) {
        const int j0 = jt * 32;
        {
            size_t rb = bh_base + (size_t)(j0 + sr) * (HH * DH) + sc;
            *(int4*)&Gs[sr][sc]  = *(const int4*)(G + rb);
            *(int4*)&GKs[sr][sc] = *(const int4*)(GK + rb);
            int4 vvec = *(const int4*)(V + rb);
            const short* vv = (const short*)&vvec;
            #pragma unroll
            for (int j = 0; j < 8; j++) Vt[sc + j][sr] = vv[j];
            if (tid < 32) Cs[tid] = Cj[((size_t)b * HH + h) * TT + j0 + tid];
        }
        __syncthreads();

        f32x4 s1[2] = {z, z}, s2[2] = {z, z};
        #pragma unroll
        for (int ns = 0; ns < 2; ns++) {
            #pragma unroll
            for (int kc = 0; kc < 2; kc++) {
                bf16x8 gf  = *(bf16x8*)&Gs [ns * 16 + l16][kc * 32 + quad * 8];
                bf16x8 gkf = *(bf16x8*)&GKs[ns * 16 + l16][kc * 32 + quad * 8];
                s1[ns] = __builtin_amdgcn_mfma_f32_16x16x32_bf16(qqf[kc], gf,  s1[ns], 0, 0, 0);
                s2[ns] = __builtin_amdgcn_mfma_f32_16x16x32_bf16(qf[kc],  gkf, s2[ns], 0, 0, 0);
            }
        }

        float p[2][4];
        float cj0 = Cs[l16], cj1 = Cs[16 + l16];
        #pragma unroll
        for (int ns = 0; ns < 2; ns++) {
            int j = j0 + ns * 16 + l16;
            float cjv = ns ? cj1 : cj0;
            #pragma unroll
            for (int r = 0; r < 4; r++) {
                int i = i0 + wave * 16 + quad * 4 + r;
                float s = (2.f * s2[ns][r] - s1[ns][r] - cjv) * 0.125f;
                p[ns][r] = (j > i) ? NEG_BIG : s;
            }
        }
        #pragma unroll
        for (int r = 0; r < 4; r++) {
            float mx = fmaxf(p[0][r], p[1][r]);
            #pragma unroll
            for (int d2 = 1; d2 < 16; d2 <<= 1) mx = fmaxf(mx, __shfl_xor(mx, d2));
            float mnew = fmaxf(m_i[r], mx);
            float corr = __expf(m_i[r] - mnew);
            float p0v = __expf(p[0][r] - mnew);
            float p1v = __expf(p[1][r] - mnew);
            p[0][r] = p0v; p[1][r] = p1v;
            float sp = p0v + p1v;
            #pragma unroll
            for (int d2 = 1; d2 < 16; d2 <<= 1) sp += __shfl_xor(sp, d2);
            l_i[r] = l_i[r] * corr + sp;
            m_i[r] = mnew;
            #pragma unroll
            for (int nv = 0; nv < 4; nv++) o_acc[nv][r] *= corr;
        }
        #pragma unroll
        for (int ns = 0; ns < 2; ns++)
            #pragma unroll
            for (int r = 0; r < 4; r++)
                Ps[wave][quad * 4 + r][ns * 16 + l16] = f2b(p[ns][r]);
        __syncthreads();

        bf16x8 pf = *(bf16x8*)&Ps[wave][l16][quad * 8];
        #pragma unroll
        for (int nv = 0; nv < 4; nv++) {
            bf16x8 vf = *(bf16x8*)&Vt[nv * 16 + l16][quad * 8];
            o_acc[nv] = __builtin_amdgcn_mfma_f32_16x16x32_bf16(pf, vf, o_acc[nv], 0, 0, 0);
        }
        __syncthreads();
    }

    #pragma unroll
    for (int nv = 0; nv < 4; nv++) {
        #pragma unroll
        for (int r = 0; r < 4; r++) {
            int i = i0 + wave * 16 + quad * 4 + r;
            int d = nv * 16 + l16;
            O[bh_base + (size_t)i * (HH * DH) + d] = f2b(o_acc[nv][r] / l_i[r]);
        }
    }
}

// ------------------------------------------------------------------ launch ---
extern "C" void kernel_launch(void* const* d_in, const int* in_sizes, int n_in,
                              void* d_out, int out_size, void* d_ws, size_t ws_size,
                              hipStream_t stream)
{
    const float* x   = (const float*)d_in[0];
    const float* n1w = (const float*)d_in[1];
    const float* n2w = (const float*)d_in[2];
    const float* wq  = (const float*)d_in[3];
    const float* wk  = (const float*)d_in[4];
    const float* wv  = (const float*)d_in[5];
    const float* wo  = (const float*)d_in[6];
    const float* mw1 = (const float*)d_in[7];
    const float* mw2 = (const float*)d_in[8];
    const float* gw  = (const float*)d_in[9];
    const float* uw  = (const float*)d_in[10];
    const float* dw  = (const float*)d_in[11];
    float* out = (float*)d_out;   // fp32; holds x2 = x + attn_out from L9 onward

    // 48 MB arena, 8 MB slots, lifetime-aliased (see analysis):
    //  slot0: h -> g -> h2 | slot1: qb -> WgT | slot2: kb/gk -> WuT
    //  slot3: vb -> WdT    | slot4: wqT|wkT|wvT|mw1T|mw2T -> ob -> F(lo)
    //  slot5: woT|m1|cj -> F(hi)
    const size_t MB = 1u << 20;
    if (ws_size < 48 * MB) return;   // diagnostic: absmax==5.375 => ws too small
    char* wsb = (char*)d_ws;
    short* h    = (short*)(wsb);
    short* g    = (short*)(wsb);
    short* h2   = (short*)(wsb);
    short* qb   = (short*)(wsb + 8 * MB);
    short* WgT  = (short*)(wsb + 8 * MB);
    short* kb   = (short*)(wsb + 16 * MB);
    short* WuT  = (short*)(wsb + 16 * MB);
    short* vb   = (short*)(wsb + 24 * MB);
    short* WdT  = (short*)(wsb + 24 * MB);
    short* wqT  = (short*)(wsb + 32 * MB);
    short* wkT  = (short*)(wsb + 34 * MB);
    short* wvT  = (short*)(wsb + 36 * MB);
    short* mw1T = (short*)(wsb + 38 * MB);
    short* mw2T = (short*)(wsb + 38 * MB + 512 * 1024);
    short* ob   = (short*)(wsb + 32 * MB);
    short* F    = (short*)(wsb + 32 * MB);   // 16 MB (slot4+slot5)
    short* woT  = (short*)(wsb + 40 * MB);
    short* m1   = (short*)(wsb + 42 * MB);
    float* cj   = (float*)(wsb + 44 * MB);

    const int M = BB * TT;  // 4096 token rows

    convT_k<<<dim3(DD / 32, DD / 32),  256, 0, stream>>>(wq,  wqT,  DD, DD);
    convT_k<<<dim3(DD / 32, DD / 32),  256, 0, stream>>>(wk,  wkT,  DD, DD);
    convT_k<<<dim3(DD / 32, DD / 32),  256, 0, stream>>>(wv,  wvT,  DD, DD);
    convT_k<<<dim3(DD / 32, DD / 32),  256, 0, stream>>>(wo,  woT,  DD, DD);
    convT_k<<<dim3(MHH / 32, DD / 32), 256, 0, stream>>>(mw1, mw1T, DD, MHH);
    convT_k<<<dim3(DD / 32, MHH / 32), 256, 0, stream>>>(mw2, mw2T, MHH, DD);

    rmsnorm_k<<<M, 256, 0, stream>>>(x, n1w, h);                                            // L1
    gemm128_k<EP_NONE,false,false>    <<<dim3(DD / 128,  M / 128), 256, 0, stream>>>(h,  wqT,  qb, nullptr, DD,  DD,  DD);  // L2
    gemm128_k<EP_NONE,false,false>    <<<dim3(DD / 128,  M / 128), 256, 0, stream>>>(h,  wkT,  kb, nullptr, DD,  DD,  DD);  // L3
    gemm128_k<EP_NONE,false,false>    <<<dim3(DD / 128,  M / 128), 256, 0, stream>>>(h,  wvT,  vb, nullptr, DD,  DD,  DD);  // L4
    gemm128_k<EP_SILU,false,false>    <<<dim3(MHH / 128, M / 128), 256, 0, stream>>>(h,  mw1T, m1, nullptr, MHH, DD,  DD);  // L5
    gemm128_k<EP_SOFTPLUS,false,false><<<dim3(DD / 128,  M / 128), 256, 0, stream>>>(m1, mw2T, g,  nullptr, DD,  MHH, MHH); // L6
    gkc_k<<<M, 256, 0, stream>>>(g, kb, cj);                                                // L7
    attn_k<<<dim3(TT / 64, BB * HH), 256, 0, stream>>>(qb, g, kb, vb, cj, ob);              // L8
    gemm128_k<EP_RES,true,true>       <<<dim3(DD / 128,  M / 128), 256, 0, stream>>>(ob, woT, out, x, DD, DD, DD);          // L9

    rmsnorm_k<<<M, 256, 0, stream>>>(out, n2w, h2);                                         // L10

    convT_k<<<dim3(DFF / 32, DD / 32), 256, 0, stream>>>(gw, WgT, DD, DFF);
    convT_k<<<dim3(DFF / 32, DD / 32), 256, 0, stream>>>(uw, WuT, DD, DFF);
    convT_k<<<dim3(DD / 32, DFF / 32), 256, 0, stream>>>(dw, WdT, DFF, DD);

    const int NH = DFF / 2;   // 2048-column halves (fits 16 MB F buffer)
    for (int half = 0; half < 2; half++) {
        const short* Gt = WgT + (size_t)half * NH * DD;
        const short* Ut = WuT + (size_t)half * NH * DD;
        gemm128_swiglu_k<<<dim3(NH / 128, M / 128), 256, 0, stream>>>(h2, Gt, Ut, F, NH, DD, DD);
        gemm128_k<EP_RES,true,true><<<dim3(DD / 128, M / 128), 256, 0, stream>>>(
            F, WdT + (size_t)half * NH, out, out, DD, NH, DFF);   // out += F @ dw_half (in-place)
    }
}

// Round 6
// 691.053 us; speedup vs baseline: 1.4597x; 1.0906x over previous
//
#include <hip/hip_runtime.h>
#include <hip/hip_bf16.h>
#include <math.h>

// Problem dims
#define BB  4
#define TT  1024
#define DD  1024
#define HH  16
#define DH  64
#define DFF 4096
#define MHH 256

typedef __attribute__((ext_vector_type(8))) short bf16x8;   // 8 bf16 = 4 VGPRs
typedef __attribute__((ext_vector_type(4))) float f32x4;
typedef unsigned int u32;

#define NEG_BIG (-1e9f)   // mask sentinel: exp underflows to 0, stays finite

__device__ __forceinline__ float b2f(short s) {
    union { unsigned int u; float f; } x;
    x.u = ((unsigned int)(unsigned short)s) << 16;
    return x.f;
}
__device__ __forceinline__ short f2b(float f) {
    union { float f; unsigned int u; } x; x.f = f;
    unsigned int r = x.u + 0x7fffu + ((x.u >> 16) & 1u);   // RNE
    return (short)(r >> 16);
}
__device__ __forceinline__ float silu_f(float x) { return x / (1.f + __expf(-x)); }

// async global->LDS, 16B per lane. LDS dest must be wave_base + lane*16.
__device__ __forceinline__ void gld16(const short* g, short* l) {
    __builtin_amdgcn_global_load_lds(
        (const __attribute__((address_space(1))) u32*)g,
        (__attribute__((address_space(3))) u32*)l, 16, 0, 0);
}

// ------------------------------------------- weight fp32 [K,N] -> bf16 [N,K]
__global__ __launch_bounds__(256) void convT_k(
    const float* __restrict__ W, short* __restrict__ Wt, int K, int N)
{
    __shared__ __align__(16) short Ts[32][36];
    const int k0 = blockIdx.y * 32, n0 = blockIdx.x * 32;
    const int r = threadIdx.x >> 3, c4 = (threadIdx.x & 7) * 4;
    float4 v = *(const float4*)(W + (size_t)(k0 + r) * N + n0 + c4);
    Ts[r][c4 + 0] = f2b(v.x); Ts[r][c4 + 1] = f2b(v.y);
    Ts[r][c4 + 2] = f2b(v.z); Ts[r][c4 + 3] = f2b(v.w);
    __syncthreads();
    short4 o;
    o.x = Ts[c4 + 0][r]; o.y = Ts[c4 + 1][r];
    o.z = Ts[c4 + 2][r]; o.w = Ts[c4 + 3][r];
    *(short4*)(Wt + (size_t)(n0 + r) * K + k0 + c4) = o;
}

// ---------------------------------------------------------------- RMSNorm ---
__global__ __launch_bounds__(256) void rmsnorm_k(
    const float* __restrict__ X, const float* __restrict__ W, short* __restrict__ O)
{
    const int row = blockIdx.x;
    const int tid = threadIdx.x;
    float4 xv = ((const float4*)(X + (size_t)row * DD))[tid];
    float f0 = xv.x, f1 = xv.y, f2 = xv.z, f3 = xv.w;
    float ss = f0*f0 + f1*f1 + f2*f2 + f3*f3;
    #pragma unroll
    for (int m = 1; m < 64; m <<= 1) ss += __shfl_xor(ss, m);
    __shared__ float red[4];
    if ((tid & 63) == 0) red[tid >> 6] = ss;
    __syncthreads();
    float tot = red[0] + red[1] + red[2] + red[3];
    float scale = rsqrtf(tot * (1.f / DD) + 1e-6f);
    float4 wv = ((const float4*)W)[tid];
    short4 ov;
    ov.x = f2b(f0 * scale * wv.x);
    ov.y = f2b(f1 * scale * wv.y);
    ov.z = f2b(f2 * scale * wv.z);
    ov.w = f2b(f3 * scale * wv.w);
    ((short4*)(O + (size_t)row * DD))[tid] = ov;
}

// ------------------------------------------------------- 128x128 MFMA GEMM --
#define EP_NONE     0
#define EP_SILU     1
#define EP_SOFTPLUS 2
#define EP_RES      3

template<int EP, bool CF32, bool AUXF32>
__global__ __launch_bounds__(256) void gemm128_k(
    const short* __restrict__ A, const short* __restrict__ Bt,
    void* Cv, const void* auxv,
    int N, int K, int ldb)            // lda = K, ldc = N
{
    __shared__ __align__(16) short As[128 * 32];
    __shared__ __align__(16) short Bs[128 * 32];
    const int tid  = threadIdx.x;
    const int wave = tid >> 6, lane = tid & 63;
    const int l16  = lane & 15, quad = lane >> 4;
    const int m0 = blockIdx.y * 128, n0 = blockIdx.x * 128;
    const int wm = (wave & 1) * 64, wn = (wave >> 1) * 64;

    f32x4 acc[4][4];
    #pragma unroll
    for (int i = 0; i < 4; i++)
        #pragma unroll
        for (int j = 0; j < 4; j++) acc[i][j] = (f32x4){0.f, 0.f, 0.f, 0.f};

    const int srow = tid >> 2, scol = (tid & 3) * 8;
    const short* ga0 = A  + (size_t)(m0 + srow)      * K   + scol;
    const short* ga1 = A  + (size_t)(m0 + 64 + srow) * K   + scol;
    const short* gb0 = Bt + (size_t)(n0 + srow)      * ldb + scol;
    const short* gb1 = Bt + (size_t)(n0 + 64 + srow) * ldb + scol;
    short* la0 = &As[tid * 8];
    short* la1 = &As[64 * 32 + tid * 8];
    short* lb0 = &Bs[tid * 8];
    short* lb1 = &Bs[64 * 32 + tid * 8];

    for (int kb = 0; kb < K; kb += 32) {
        gld16(ga0 + kb, la0);
        gld16(ga1 + kb, la1);
        gld16(gb0 + kb, lb0);
        gld16(gb1 + kb, lb1);
        __syncthreads();
        bf16x8 af[4], bf[4];
        #pragma unroll
        for (int mi = 0; mi < 4; mi++)
            af[mi] = *(bf16x8*)&As[(wm + mi * 16 + l16) * 32 + quad * 8];
        #pragma unroll
        for (int ni = 0; ni < 4; ni++)
            bf[ni] = *(bf16x8*)&Bs[(wn + ni * 16 + l16) * 32 + quad * 8];
        #pragma unroll
        for (int mi = 0; mi < 4; mi++)
            #pragma unroll
            for (int ni = 0; ni < 4; ni++)
                acc[mi][ni] = __builtin_amdgcn_mfma_f32_16x16x32_bf16(af[mi], bf[ni], acc[mi][ni], 0, 0, 0);
        __syncthreads();
    }
    #pragma unroll
    for (int mi = 0; mi < 4; mi++) {
        #pragma unroll
        for (int ni = 0; ni < 4; ni++) {
            #pragma unroll
            for (int r = 0; r < 4; r++) {
                int row = m0 + wm + mi * 16 + quad * 4 + r;
                int col = n0 + wn + ni * 16 + l16;
                size_t idx = (size_t)row * N + col;
                float v = acc[mi][ni][r];
                if (EP == EP_SILU)          v = silu_f(v);
                else if (EP == EP_SOFTPLUS) v = fmaxf(v, 0.f) + log1pf(__expf(-fabsf(v)));
                else if (EP == EP_RES) {
                    if (AUXF32) v += ((const float*)auxv)[idx];
                    else        v += b2f(((const short*)auxv)[idx]);
                }
                if (CF32) ((float*)Cv)[idx] = v;
                else      ((short*)Cv)[idx] = f2b(v);
            }
        }
    }
}

// ----------------------------------- 128x128 fused SwiGLU (gate & up) GEMM --
__global__ __launch_bounds__(256) void gemm128_swiglu_k(
    const short* __restrict__ A, const short* __restrict__ Gt,
    const short* __restrict__ Ut, short* __restrict__ F,
    int N, int K, int ldb)
{
    __shared__ __align__(16) short As[128 * 32];
    __shared__ __align__(16) short Gs[128 * 32];
    __shared__ __align__(16) short Us[128 * 32];
    const int tid  = threadIdx.x;
    const int wave = tid >> 6, lane = tid & 63;
    const int l16  = lane & 15, quad = lane >> 4;
    const int m0 = blockIdx.y * 128, n0 = blockIdx.x * 128;
    const int wm = (wave & 1) * 64, wn = (wave >> 1) * 64;

    f32x4 ag[4][4], au[4][4];
    #pragma unroll
    for (int i = 0; i < 4; i++)
        #pragma unroll
        for (int j = 0; j < 4; j++) {
            ag[i][j] = (f32x4){0.f, 0.f, 0.f, 0.f};
            au[i][j] = (f32x4){0.f, 0.f, 0.f, 0.f};
        }

    const int srow = tid >> 2, scol = (tid & 3) * 8;
    const short* ga0 = A  + (size_t)(m0 + srow)      * K   + scol;
    const short* ga1 = A  + (size_t)(m0 + 64 + srow) * K   + scol;
    const short* gg0 = Gt + (size_t)(n0 + srow)      * ldb + scol;
    const short* gg1 = Gt + (size_t)(n0 + 64 + srow) * ldb + scol;
    const short* gu0 = Ut + (size_t)(n0 + srow)      * ldb + scol;
    const short* gu1 = Ut + (size_t)(n0 + 64 + srow) * ldb + scol;
    short* la0 = &As[tid * 8];
    short* la1 = &As[64 * 32 + tid * 8];
    short* lg0 = &Gs[tid * 8];
    short* lg1 = &Gs[64 * 32 + tid * 8];
    short* lu0 = &Us[tid * 8];
    short* lu1 = &Us[64 * 32 + tid * 8];

    for (int kb = 0; kb < K; kb += 32) {
        gld16(ga0 + kb, la0);
        gld16(ga1 + kb, la1);
        gld16(gg0 + kb, lg0);
        gld16(gg1 + kb, lg1);
        gld16(gu0 + kb, lu0);
        gld16(gu1 + kb, lu1);
        __syncthreads();
        bf16x8 af[4], gf[4], uf[4];
        #pragma unroll
        for (int mi = 0; mi < 4; mi++)
            af[mi] = *(bf16x8*)&As[(wm + mi * 16 + l16) * 32 + quad * 8];
        #pragma unroll
        for (int ni = 0; ni < 4; ni++) {
            gf[ni] = *(bf16x8*)&Gs[(wn + ni * 16 + l16) * 32 + quad * 8];
            uf[ni] = *(bf16x8*)&Us[(wn + ni * 16 + l16) * 32 + quad * 8];
        }
        #pragma unroll
        for (int mi = 0; mi < 4; mi++)
            #pragma unroll
            for (int ni = 0; ni < 4; ni++) {
                ag[mi][ni] = __builtin_amdgcn_mfma_f32_16x16x32_bf16(af[mi], gf[ni], ag[mi][ni], 0, 0, 0);
                au[mi][ni] = __builtin_amdgcn_mfma_f32_16x16x32_bf16(af[mi], uf[ni], au[mi][ni], 0, 0, 0);
            }
        __syncthreads();
    }
    #pragma unroll
    for (int mi = 0; mi < 4; mi++)
        #pragma unroll
        for (int ni = 0; ni < 4; ni++)
            #pragma unroll
            for (int r = 0; r < 4; r++) {
                int row = m0 + wm + mi * 16 + quad * 4 + r;
                int col = n0 + wn + ni * 16 + l16;
                F[(size_t)row * N + col] = f2b(silu_f(ag[mi][ni][r]) * au[mi][ni][r]);
            }
}

// ------------------------------------- gk = g*k in-place, c = sum gk*k ------
__global__ __launch_bounds__(256) void gkc_k(
    const short* __restrict__ G, short* KG,
    float* __restrict__ Cj)
{
    const int bt  = blockIdx.x;
    const int tid = threadIdx.x;
    const int h = tid >> 4, d0 = (tid & 15) * 4;
    const size_t base = (size_t)bt * (HH * DH) + h * DH + d0;
    short4 gv = *(const short4*)(G + base);
    short4 kv = *(const short4*)(KG + base);
    float g0 = b2f(gv.x), g1 = b2f(gv.y), g2 = b2f(gv.z), g3 = b2f(gv.w);
    float k0 = b2f(kv.x), k1 = b2f(kv.y), k2 = b2f(kv.z), k3 = b2f(kv.w);
    float p0 = g0*k0, p1 = g1*k1, p2 = g2*k2, p3 = g3*k3;
    short4 ov; ov.x = f2b(p0); ov.y = f2b(p1); ov.z = f2b(p2); ov.w = f2b(p3);
    *(short4*)(KG + base) = ov;
    float cc = p0*k0 + p1*k1 + p2*k2 + p3*k3;
    #pragma unroll
    for (int m = 1; m < 16; m <<= 1) cc += __shfl_xor(cc, m);
    if ((tid & 15) == 0) {
        int b = bt >> 10, t = bt & (TT - 1);
        Cj[((size_t)b * HH + h) * TT + t] = cc;
    }
}

// -------------------------------------------------- flash geodesic attention -
// Triangle-paired: block (p, bh) processes i-tiles p and 15-p sequentially ->
// constant 17 j-tile(64) units per block (perfect causal load balance).
// scores = (2*q.gk^T - qq.g^T - c_j) / 8, online softmax, O = P.V
__global__ __launch_bounds__(256) void attn_k(
    const short* __restrict__ Q, const short* __restrict__ G,
    const short* __restrict__ GK, const short* __restrict__ V,
    const float* __restrict__ Cj, short* __restrict__ O)
{
    __shared__ __align__(16) short Gs[64][72];    // [j][d] +8 pad
    __shared__ __align__(16) short GKs[64][72];
    __shared__ __align__(16) short Vt[64][72];    // transposed: [d][j]
    __shared__ __align__(16) float Cs[64];
    __shared__ __align__(16) short Ps[4][16][72]; // per-wave P (16x64), C->A layout

    const int pair = blockIdx.x;          // 0..7
    const int bh = blockIdx.y;
    const int b = bh >> 4, h = bh & 15;
    const int tid  = threadIdx.x;
    const int wave = tid >> 6, lane = tid & 63;
    const int l16  = lane & 15, quad = lane >> 4;

    const size_t bh_base = ((size_t)b * TT) * (HH * DH) + (size_t)h * DH;
    const float* cj_row = Cj + ((size_t)b * HH + h) * TT;

    const int sr2 = tid >> 3, sc2 = (tid & 7) * 8;   // staging: 32 rows x 64 cols/pass
    const f32x4 z = {0.f, 0.f, 0.f, 0.f};

    for (int halfsel = 0; halfsel < 2; halfsel++) {
        const int it = halfsel ? 15 - pair : pair;
        const int i0 = it * 64;

        // Q fragments (A-layout, 2 d-chunks) for this tile
        const int qrow = i0 + wave * 16 + l16;
        bf16x8 qf[2], qqf[2];
        #pragma unroll
        for (int kc = 0; kc < 2; kc++) {
            qf[kc] = *(const bf16x8*)(Q + bh_base + (size_t)qrow * (HH * DH) + kc * 32 + quad * 8);
            #pragma unroll
            for (int j = 0; j < 8; j++) {
                float f = b2f(qf[kc][j]);
                qqf[kc][j] = f2b(f * f);
            }
        }

        float m_i[4], l_i[4];
        f32x4 o_acc[4] = {z, z, z, z};
        #pragma unroll
        for (int r = 0; r < 4; r++) { m_i[r] = NEG_BIG; l_i[r] = 0.f; }

        for (int jt = 0; jt <= it; jt++) {
            const int j0 = jt * 64;
            // ---- stage G, GK, V^T, Cs (2 passes of 32 rows) ----
            #pragma unroll
            for (int pass = 0; pass < 2; pass++) {
                int jr = sr2 + pass * 32;
                size_t rb = bh_base + (size_t)(j0 + jr) * (HH * DH) + sc2;
                *(int4*)&Gs[jr][sc2]  = *(const int4*)(G + rb);
                *(int4*)&GKs[jr][sc2] = *(const int4*)(GK + rb);
                int4 vvec = *(const int4*)(V + rb);
                const short* vv = (const short*)&vvec;
                #pragma unroll
                for (int jj = 0; jj < 8; jj++) Vt[sc2 + jj][jr] = vv[jj];
            }
            if (tid < 64) Cs[tid] = cj_row[j0 + tid];
            __syncthreads();

            // ---- S = 2*q.gk^T - qq.g^T - c_j : 4 n-subtiles x 2 d-chunks ----
            f32x4 s1[4] = {z, z, z, z}, s2[4] = {z, z, z, z};
            #pragma unroll
            for (int ns = 0; ns < 4; ns++) {
                #pragma unroll
                for (int kc = 0; kc < 2; kc++) {
                    bf16x8 gf  = *(bf16x8*)&Gs [ns * 16 + l16][kc * 32 + quad * 8];
                    bf16x8 gkf = *(bf16x8*)&GKs[ns * 16 + l16][kc * 32 + quad * 8];
                    s1[ns] = __builtin_amdgcn_mfma_f32_16x16x32_bf16(qqf[kc], gf,  s1[ns], 0, 0, 0);
                    s2[ns] = __builtin_amdgcn_mfma_f32_16x16x32_bf16(qf[kc],  gkf, s2[ns], 0, 0, 0);
                }
            }

            // ---- scores (+ causal mask on the diagonal tile only) ----
            float p[4][4];
            #pragma unroll
            for (int ns = 0; ns < 4; ns++) {
                float cjv = Cs[ns * 16 + l16];
                #pragma unroll
                for (int r = 0; r < 4; r++)
                    p[ns][r] = (2.f * s2[ns][r] - s1[ns][r] - cjv) * 0.125f;
            }
            if (jt == it) {   // wave-uniform branch
                #pragma unroll
                for (int ns = 0; ns < 4; ns++) {
                    int j = j0 + ns * 16 + l16;
                    #pragma unroll
                    for (int r = 0; r < 4; r++) {
                        int i = i0 + wave * 16 + quad * 4 + r;
                        if (j > i) p[ns][r] = NEG_BIG;
                    }
                }
            }

            // ---- online softmax per row ----
            #pragma unroll
            for (int r = 0; r < 4; r++) {
                float mx = fmaxf(fmaxf(p[0][r], p[1][r]), fmaxf(p[2][r], p[3][r]));
                #pragma unroll
                for (int d2 = 1; d2 < 16; d2 <<= 1) mx = fmaxf(mx, __shfl_xor(mx, d2));
                float mnew = fmaxf(m_i[r], mx);
                float corr = __expf(m_i[r] - mnew);
                float sp = 0.f;
                #pragma unroll
                for (int ns = 0; ns < 4; ns++) {
                    float e = __expf(p[ns][r] - mnew);
                    p[ns][r] = e; sp += e;
                }
                #pragma unroll
                for (int d2 = 1; d2 < 16; d2 <<= 1) sp += __shfl_xor(sp, d2);
                l_i[r] = l_i[r] * corr + sp;
                m_i[r] = mnew;
                #pragma unroll
                for (int nv = 0; nv < 4; nv++) o_acc[nv][r] *= corr;
            }

            // ---- P: C-layout -> per-wave LDS -> A-layout (no barrier needed:
            //      Ps[wave] is wave-private; same-wave RAW ordered by lgkmcnt) ----
            #pragma unroll
            for (int ns = 0; ns < 4; ns++)
                #pragma unroll
                for (int r = 0; r < 4; r++)
                    Ps[wave][quad * 4 + r][ns * 16 + l16] = f2b(p[ns][r]);

            bf16x8 pf[2];
            pf[0] = *(bf16x8*)&Ps[wave][l16][quad * 8];
            pf[1] = *(bf16x8*)&Ps[wave][l16][32 + quad * 8];
            #pragma unroll
            for (int nv = 0; nv < 4; nv++) {
                #pragma unroll
                for (int kc = 0; kc < 2; kc++) {
                    bf16x8 vf = *(bf16x8*)&Vt[nv * 16 + l16][kc * 32 + quad * 8];
                    o_acc[nv] = __builtin_amdgcn_mfma_f32_16x16x32_bf16(pf[kc], vf, o_acc[nv], 0, 0, 0);
                }
            }
            __syncthreads();   // all waves done with Gs/GKs/Vt before restaging
        }

        #pragma unroll
        for (int nv = 0; nv < 4; nv++) {
            #pragma unroll
            for (int r = 0; r < 4; r++) {
                int i = i0 + wave * 16 + quad * 4 + r;
                int d = nv * 16 + l16;
                O[bh_base + (size_t)i * (HH * DH) + d] = f2b(o_acc[nv][r] / l_i[r]);
            }
        }
    }
}

// ------------------------------------------------------------------ launch ---
extern "C" void kernel_launch(void* const* d_in, const int* in_sizes, int n_in,
                              void* d_out, int out_size, void* d_ws, size_t ws_size,
                              hipStream_t stream)
{
    const float* x   = (const float*)d_in[0];
    const float* n1w = (const float*)d_in[1];
    const float* n2w = (const float*)d_in[2];
    const float* wq  = (const float*)d_in[3];
    const float* wk  = (const float*)d_in[4];
    const float* wv  = (const float*)d_in[5];
    const float* wo  = (const float*)d_in[6];
    const float* mw1 = (const float*)d_in[7];
    const float* mw2 = (const float*)d_in[8];
    const float* gw  = (const float*)d_in[9];
    const float* uw  = (const float*)d_in[10];
    const float* dw  = (const float*)d_in[11];
    float* out = (float*)d_out;   // fp32; holds x2 = x + attn_out from L9 onward

    // 48 MB arena, 8 MB slots, lifetime-aliased:
    //  slot0: h -> g -> h2 | slot1: qb -> WgT | slot2: kb/gk -> WuT
    //  slot3: vb -> WdT    | slot4: wqT|wkT|wvT|mw1T|mw2T -> ob -> F(lo)
    //  slot5: woT|m1|cj -> F(hi)
    const size_t MB = 1u << 20;
    if (ws_size < 48 * MB) return;   // diagnostic: absmax==5.375 => ws too small
    char* wsb = (char*)d_ws;
    short* h    = (short*)(wsb);
    short* g    = (short*)(wsb);
    short* h2   = (short*)(wsb);
    short* qb   = (short*)(wsb + 8 * MB);
    short* WgT  = (short*)(wsb + 8 * MB);
    short* kb   = (short*)(wsb + 16 * MB);
    short* WuT  = (short*)(wsb + 16 * MB);
    short* vb   = (short*)(wsb + 24 * MB);
    short* WdT  = (short*)(wsb + 24 * MB);
    short* wqT  = (short*)(wsb + 32 * MB);
    short* wkT  = (short*)(wsb + 34 * MB);
    short* wvT  = (short*)(wsb + 36 * MB);
    short* mw1T = (short*)(wsb + 38 * MB);
    short* mw2T = (short*)(wsb + 38 * MB + 512 * 1024);
    short* ob   = (short*)(wsb + 32 * MB);
    short* F    = (short*)(wsb + 32 * MB);   // 16 MB (slot4+slot5)
    short* woT  = (short*)(wsb + 40 * MB);
    short* m1   = (short*)(wsb + 42 * MB);
    float* cj   = (float*)(wsb + 44 * MB);

    const int M = BB * TT;  // 4096 token rows

    convT_k<<<dim3(DD / 32, DD / 32),  256, 0, stream>>>(wq,  wqT,  DD, DD);
    convT_k<<<dim3(DD / 32, DD / 32),  256, 0, stream>>>(wk,  wkT,  DD, DD);
    convT_k<<<dim3(DD / 32, DD / 32),  256, 0, stream>>>(wv,  wvT,  DD, DD);
    convT_k<<<dim3(DD / 32, DD / 32),  256, 0, stream>>>(wo,  woT,  DD, DD);
    convT_k<<<dim3(MHH / 32, DD / 32), 256, 0, stream>>>(mw1, mw1T, DD, MHH);
    convT_k<<<dim3(DD / 32, MHH / 32), 256, 0, stream>>>(mw2, mw2T, MHH, DD);

    rmsnorm_k<<<M, 256, 0, stream>>>(x, n1w, h);                                            // L1
    gemm128_k<EP_NONE,false,false>    <<<dim3(DD / 128,  M / 128), 256, 0, stream>>>(h,  wqT,  qb, nullptr, DD,  DD,  DD);  // L2
    gemm128_k<EP_NONE,false,false>    <<<dim3(DD / 128,  M / 128), 256, 0, stream>>>(h,  wkT,  kb, nullptr, DD,  DD,  DD);  // L3
    gemm128_k<EP_NONE,false,false>    <<<dim3(DD / 128,  M / 128), 256, 0, stream>>>(h,  wvT,  vb, nullptr, DD,  DD,  DD);  // L4
    gemm128_k<EP_SILU,false,false>    <<<dim3(MHH / 128, M / 128), 256, 0, stream>>>(h,  mw1T, m1, nullptr, MHH, DD,  DD);  // L5
    gemm128_k<EP_SOFTPLUS,false,false><<<dim3(DD / 128,  M / 128), 256, 0, stream>>>(m1, mw2T, g,  nullptr, DD,  MHH, MHH); // L6
    gkc_k<<<M, 256, 0, stream>>>(g, kb, cj);                                                // L7
    attn_k<<<dim3(8, BB * HH), 256, 0, stream>>>(qb, g, kb, vb, cj, ob);                    // L8
    gemm128_k<EP_RES,true,true>       <<<dim3(DD / 128,  M / 128), 256, 0, stream>>>(ob, woT, out, x, DD, DD, DD);          // L9

    rmsnorm_k<<<M, 256, 0, stream>>>(out, n2w, h2);                                         // L10

    convT_k<<<dim3(DFF / 32, DD / 32), 256, 0, stream>>>(gw, WgT, DD, DFF);
    convT_k<<<dim3(DFF / 32, DD / 32), 256, 0, stream>>>(uw, WuT, DD, DFF);
    convT_k<<<dim3(DD / 32, DFF / 32), 256, 0, stream>>>(dw, WdT, DFF, DD);

    const int NH = DFF / 2;   // 2048-column halves (fits 16 MB F buffer)
    for (int half = 0; half < 2; half++) {
        const short* Gt = WgT + (size_t)half * NH * DD;
        const short* Ut = WuT + (size_t)half * NH * DD;
        gemm128_swiglu_k<<<dim3(NH / 128, M / 128), 256, 0, stream>>>(h2, Gt, Ut, F, NH, DD, DD);
        gemm128_k<EP_RES,true,true><<<dim3(DD / 128, M / 128), 256, 0, stream>>>(
            F, WdT + (size_t)half * NH, out, out, DD, NH, DFF);   // out += F @ dw_half (in-place)
    }
}

// Round 7
// 609.088 us; speedup vs baseline: 1.6562x; 1.1346x over previous
//
#include <hip/hip_runtime.h>
#include <hip/hip_bf16.h>
#include <math.h>

// Problem dims
#define BB  4
#define TT  1024
#define DD  1024
#define HH  16
#define DH  64
#define DFF 4096
#define MHH 256

typedef __attribute__((ext_vector_type(8))) short bf16x8;   // 8 bf16 = 4 VGPRs
typedef __attribute__((ext_vector_type(4))) float f32x4;
typedef unsigned int u32;

#define NEG_BIG (-1e9f)

__device__ __forceinline__ float b2f(short s) {
    union { unsigned int u; float f; } x;
    x.u = ((unsigned int)(unsigned short)s) << 16;
    return x.f;
}
__device__ __forceinline__ short f2b(float f) {
    union { float f; unsigned int u; } x; x.f = f;
    unsigned int r = x.u + 0x7fffu + ((x.u >> 16) & 1u);   // RNE
    return (short)(r >> 16);
}
__device__ __forceinline__ float silu_f(float x) { return x / (1.f + __expf(-x)); }

// async global->LDS, 16B per lane. LDS dest must be wave_base + lane*16.
__device__ __forceinline__ void gld16(const short* g, short* l) {
    __builtin_amdgcn_global_load_lds(
        (const __attribute__((address_space(1))) u32*)g,
        (__attribute__((address_space(3))) u32*)l, 16, 0, 0);
}

// ------------------------------------------- weight fp32 [K,N] -> bf16 [N,K]
__global__ __launch_bounds__(256) void convT_k(
    const float* __restrict__ W, short* __restrict__ Wt, int K, int N)
{
    __shared__ __align__(16) short Ts[32][36];
    const int k0 = blockIdx.y * 32, n0 = blockIdx.x * 32;
    const int r = threadIdx.x >> 3, c4 = (threadIdx.x & 7) * 4;
    float4 v = *(const float4*)(W + (size_t)(k0 + r) * N + n0 + c4);
    Ts[r][c4 + 0] = f2b(v.x); Ts[r][c4 + 1] = f2b(v.y);
    Ts[r][c4 + 2] = f2b(v.z); Ts[r][c4 + 3] = f2b(v.w);
    __syncthreads();
    short4 o;
    o.x = Ts[c4 + 0][r]; o.y = Ts[c4 + 1][r];
    o.z = Ts[c4 + 2][r]; o.w = Ts[c4 + 3][r];
    *(short4*)(Wt + (size_t)(n0 + r) * K + k0 + c4) = o;
}

// ---------------------------------------------------------------- RMSNorm ---
__global__ __launch_bounds__(256) void rmsnorm_k(
    const float* __restrict__ X, const float* __restrict__ W, short* __restrict__ O)
{
    const int row = blockIdx.x;
    const int tid = threadIdx.x;
    float4 xv = ((const float4*)(X + (size_t)row * DD))[tid];
    float f0 = xv.x, f1 = xv.y, f2 = xv.z, f3 = xv.w;
    float ss = f0*f0 + f1*f1 + f2*f2 + f3*f3;
    #pragma unroll
    for (int m = 1; m < 64; m <<= 1) ss += __shfl_xor(ss, m);
    __shared__ float red[4];
    if ((tid & 63) == 0) red[tid >> 6] = ss;
    __syncthreads();
    float tot = red[0] + red[1] + red[2] + red[3];
    float scale = rsqrtf(tot * (1.f / DD) + 1e-6f);
    float4 wv = ((const float4*)W)[tid];
    short4 ov;
    ov.x = f2b(f0 * scale * wv.x);
    ov.y = f2b(f1 * scale * wv.y);
    ov.z = f2b(f2 * scale * wv.z);
    ov.w = f2b(f3 * scale * wv.w);
    ((short4*)(O + (size_t)row * DD))[tid] = ov;
}

// ------------------------------------------------------- 128x128 MFMA GEMM --
#define EP_NONE     0
#define EP_SILU     1
#define EP_SOFTPLUS 2
#define EP_RES      3

template<int EP, bool CF32, bool AUXF32>
__global__ __launch_bounds__(256) void gemm128_k(
    const short* __restrict__ A, const short* __restrict__ Bt,
    void* Cv, const void* auxv,
    int N, int K, int lda, int ldb)
{
    __shared__ __align__(16) short As[128 * 32];
    __shared__ __align__(16) short Bs[128 * 32];
    const int tid  = threadIdx.x;
    const int wave = tid >> 6, lane = tid & 63;
    const int l16  = lane & 15, quad = lane >> 4;
    const int m0 = blockIdx.y * 128, n0 = blockIdx.x * 128;
    const int wm = (wave & 1) * 64, wn = (wave >> 1) * 64;

    f32x4 acc[4][4];
    #pragma unroll
    for (int i = 0; i < 4; i++)
        #pragma unroll
        for (int j = 0; j < 4; j++) acc[i][j] = (f32x4){0.f, 0.f, 0.f, 0.f};

    const int srow = tid >> 2, scol = (tid & 3) * 8;
    const short* ga0 = A  + (size_t)(m0 + srow)      * lda + scol;
    const short* ga1 = A  + (size_t)(m0 + 64 + srow) * lda + scol;
    const short* gb0 = Bt + (size_t)(n0 + srow)      * ldb + scol;
    const short* gb1 = Bt + (size_t)(n0 + 64 + srow) * ldb + scol;
    short* la0 = &As[tid * 8];
    short* la1 = &As[64 * 32 + tid * 8];
    short* lb0 = &Bs[tid * 8];
    short* lb1 = &Bs[64 * 32 + tid * 8];

    for (int kb = 0; kb < K; kb += 32) {
        gld16(ga0 + kb, la0);
        gld16(ga1 + kb, la1);
        gld16(gb0 + kb, lb0);
        gld16(gb1 + kb, lb1);
        __syncthreads();
        bf16x8 af[4], bf[4];
        #pragma unroll
        for (int mi = 0; mi < 4; mi++)
            af[mi] = *(bf16x8*)&As[(wm + mi * 16 + l16) * 32 + quad * 8];
        #pragma unroll
        for (int ni = 0; ni < 4; ni++)
            bf[ni] = *(bf16x8*)&Bs[(wn + ni * 16 + l16) * 32 + quad * 8];
        #pragma unroll
        for (int mi = 0; mi < 4; mi++)
            #pragma unroll
            for (int ni = 0; ni < 4; ni++)
                acc[mi][ni] = __builtin_amdgcn_mfma_f32_16x16x32_bf16(af[mi], bf[ni], acc[mi][ni], 0, 0, 0);
        __syncthreads();
    }
    #pragma unroll
    for (int mi = 0; mi < 4; mi++) {
        #pragma unroll
        for (int ni = 0; ni < 4; ni++) {
            #pragma unroll
            for (int r = 0; r < 4; r++) {
                int row = m0 + wm + mi * 16 + quad * 4 + r;
                int col = n0 + wn + ni * 16 + l16;
                size_t idx = (size_t)row * N + col;
                float v = acc[mi][ni][r];
                if (EP == EP_SILU)          v = silu_f(v);
                else if (EP == EP_SOFTPLUS) v = fmaxf(v, 0.f) + log1pf(__expf(-fabsf(v)));
                else if (EP == EP_RES) {
                    if (AUXF32) v += ((const float*)auxv)[idx];
                    else        v += b2f(((const short*)auxv)[idx]);
                }
                if (CF32) ((float*)Cv)[idx] = v;
                else      ((short*)Cv)[idx] = f2b(v);
            }
        }
    }
}

// -------------------- split-K 128x128 GEMM, fp32 atomic accumulate into out --
__global__ __launch_bounds__(256) void gemm128_atomic_k(
    const short* __restrict__ A, const short* __restrict__ Bt,
    float* out, int N, int Kc, int lda, int ldb)
{
    __shared__ __align__(16) short As[128 * 32];
    __shared__ __align__(16) short Bs[128 * 32];
    const int tid  = threadIdx.x;
    const int wave = tid >> 6, lane = tid & 63;
    const int l16  = lane & 15, quad = lane >> 4;
    const int m0 = blockIdx.y * 128, n0 = blockIdx.x * 128;
    const int wm = (wave & 1) * 64, wn = (wave >> 1) * 64;
    const int koff = blockIdx.z * Kc;

    f32x4 acc[4][4];
    #pragma unroll
    for (int i = 0; i < 4; i++)
        #pragma unroll
        for (int j = 0; j < 4; j++) acc[i][j] = (f32x4){0.f, 0.f, 0.f, 0.f};

    const int srow = tid >> 2, scol = (tid & 3) * 8;
    const short* ga0 = A  + (size_t)(m0 + srow)      * lda + koff + scol;
    const short* ga1 = A  + (size_t)(m0 + 64 + srow) * lda + koff + scol;
    const short* gb0 = Bt + (size_t)(n0 + srow)      * ldb + koff + scol;
    const short* gb1 = Bt + (size_t)(n0 + 64 + srow) * ldb + koff + scol;
    short* la0 = &As[tid * 8];
    short* la1 = &As[64 * 32 + tid * 8];
    short* lb0 = &Bs[tid * 8];
    short* lb1 = &Bs[64 * 32 + tid * 8];

    for (int kb = 0; kb < Kc; kb += 32) {
        gld16(ga0 + kb, la0);
        gld16(ga1 + kb, la1);
        gld16(gb0 + kb, lb0);
        gld16(gb1 + kb, lb1);
        __syncthreads();
        bf16x8 af[4], bf[4];
        #pragma unroll
        for (int mi = 0; mi < 4; mi++)
            af[mi] = *(bf16x8*)&As[(wm + mi * 16 + l16) * 32 + quad * 8];
        #pragma unroll
        for (int ni = 0; ni < 4; ni++)
            bf[ni] = *(bf16x8*)&Bs[(wn + ni * 16 + l16) * 32 + quad * 8];
        #pragma unroll
        for (int mi = 0; mi < 4; mi++)
            #pragma unroll
            for (int ni = 0; ni < 4; ni++)
                acc[mi][ni] = __builtin_amdgcn_mfma_f32_16x16x32_bf16(af[mi], bf[ni], acc[mi][ni], 0, 0, 0);
        __syncthreads();
    }
    #pragma unroll
    for (int mi = 0; mi < 4; mi++)
        #pragma unroll
        for (int ni = 0; ni < 4; ni++)
            #pragma unroll
            for (int r = 0; r < 4; r++) {
                int row = m0 + wm + mi * 16 + quad * 4 + r;
                int col = n0 + wn + ni * 16 + l16;
                atomicAdd(out + (size_t)row * N + col, acc[mi][ni][r]);
            }
}

// --------------- fused QKV+mnet1 GEMM: N=3328 packed weights, routed epilogue
// Wf rows: [0,1024)=wq^T, [1024,2048)=wk^T, [2048,3072)=wv^T, [3072,3328)=mw1^T
__global__ __launch_bounds__(256) void gemm128_qkvm_k(
    const short* __restrict__ A, const short* __restrict__ Wf,
    short* __restrict__ Qb, short* __restrict__ Kb, short* __restrict__ Vb,
    short* __restrict__ M1)
{
    __shared__ __align__(16) short As[128 * 32];
    __shared__ __align__(16) short Bs[128 * 32];
    const int tid  = threadIdx.x;
    const int wave = tid >> 6, lane = tid & 63;
    const int l16  = lane & 15, quad = lane >> 4;
    const int m0 = blockIdx.y * 128, n0 = blockIdx.x * 128;
    const int wm = (wave & 1) * 64, wn = (wave >> 1) * 64;
    const int K = DD;

    f32x4 acc[4][4];
    #pragma unroll
    for (int i = 0; i < 4; i++)
        #pragma unroll
        for (int j = 0; j < 4; j++) acc[i][j] = (f32x4){0.f, 0.f, 0.f, 0.f};

    const int srow = tid >> 2, scol = (tid & 3) * 8;
    const short* ga0 = A  + (size_t)(m0 + srow)      * K + scol;
    const short* ga1 = A  + (size_t)(m0 + 64 + srow) * K + scol;
    const short* gb0 = Wf + (size_t)(n0 + srow)      * K + scol;
    const short* gb1 = Wf + (size_t)(n0 + 64 + srow) * K + scol;
    short* la0 = &As[tid * 8];
    short* la1 = &As[64 * 32 + tid * 8];
    short* lb0 = &Bs[tid * 8];
    short* lb1 = &Bs[64 * 32 + tid * 8];

    for (int kb = 0; kb < K; kb += 32) {
        gld16(ga0 + kb, la0);
        gld16(ga1 + kb, la1);
        gld16(gb0 + kb, lb0);
        gld16(gb1 + kb, lb1);
        __syncthreads();
        bf16x8 af[4], bf[4];
        #pragma unroll
        for (int mi = 0; mi < 4; mi++)
            af[mi] = *(bf16x8*)&As[(wm + mi * 16 + l16) * 32 + quad * 8];
        #pragma unroll
        for (int ni = 0; ni < 4; ni++)
            bf[ni] = *(bf16x8*)&Bs[(wn + ni * 16 + l16) * 32 + quad * 8];
        #pragma unroll
        for (int mi = 0; mi < 4; mi++)
            #pragma unroll
            for (int ni = 0; ni < 4; ni++)
                acc[mi][ni] = __builtin_amdgcn_mfma_f32_16x16x32_bf16(af[mi], bf[ni], acc[mi][ni], 0, 0, 0);
        __syncthreads();
    }
    short* dst; int base, ldc; bool dosilu = false;
    if      (n0 < 1024) { dst = Qb; base = 0;    ldc = 1024; }
    else if (n0 < 2048) { dst = Kb; base = 1024; ldc = 1024; }
    else if (n0 < 3072) { dst = Vb; base = 2048; ldc = 1024; }
    else                { dst = M1; base = 3072; ldc = 256; dosilu = true; }
    #pragma unroll
    for (int mi = 0; mi < 4; mi++)
        #pragma unroll
        for (int ni = 0; ni < 4; ni++)
            #pragma unroll
            for (int r = 0; r < 4; r++) {
                int row = m0 + wm + mi * 16 + quad * 4 + r;
                int col = n0 + wn + ni * 16 + l16 - base;
                float v = acc[mi][ni][r];
                if (dosilu) v = silu_f(v);
                dst[(size_t)row * ldc + col] = f2b(v);
            }
}

// ----------------------------------- 128x128 fused SwiGLU (gate & up) GEMM --
__global__ __launch_bounds__(256) void gemm128_swiglu_k(
    const short* __restrict__ A, const short* __restrict__ Gt,
    const short* __restrict__ Ut, short* __restrict__ F,
    int N, int K, int ldb)
{
    __shared__ __align__(16) short As[128 * 32];
    __shared__ __align__(16) short Gs[128 * 32];
    __shared__ __align__(16) short Us[128 * 32];
    const int tid  = threadIdx.x;
    const int wave = tid >> 6, lane = tid & 63;
    const int l16  = lane & 15, quad = lane >> 4;
    const int m0 = blockIdx.y * 128, n0 = blockIdx.x * 128;
    const int wm = (wave & 1) * 64, wn = (wave >> 1) * 64;

    f32x4 ag[4][4], au[4][4];
    #pragma unroll
    for (int i = 0; i < 4; i++)
        #pragma unroll
        for (int j = 0; j < 4; j++) {
            ag[i][j] = (f32x4){0.f, 0.f, 0.f, 0.f};
            au[i][j] = (f32x4){0.f, 0.f, 0.f, 0.f};
        }

    const int srow = tid >> 2, scol = (tid & 3) * 8;
    const short* ga0 = A  + (size_t)(m0 + srow)      * K   + scol;
    const short* ga1 = A  + (size_t)(m0 + 64 + srow) * K   + scol;
    const short* gg0 = Gt + (size_t)(n0 + srow)      * ldb + scol;
    const short* gg1 = Gt + (size_t)(n0 + 64 + srow) * ldb + scol;
    const short* gu0 = Ut + (size_t)(n0 + srow)      * ldb + scol;
    const short* gu1 = Ut + (size_t)(n0 + 64 + srow) * ldb + scol;
    short* la0 = &As[tid * 8];
    short* la1 = &As[64 * 32 + tid * 8];
    short* lg0 = &Gs[tid * 8];
    short* lg1 = &Gs[64 * 32 + tid * 8];
    short* lu0 = &Us[tid * 8];
    short* lu1 = &Us[64 * 32 + tid * 8];

    for (int kb = 0; kb < K; kb += 32) {
        gld16(ga0 + kb, la0);
        gld16(ga1 + kb, la1);
        gld16(gg0 + kb, lg0);
        gld16(gg1 + kb, lg1);
        gld16(gu0 + kb, lu0);
        gld16(gu1 + kb, lu1);
        __syncthreads();
        bf16x8 af[4], gf[4], uf[4];
        #pragma unroll
        for (int mi = 0; mi < 4; mi++)
            af[mi] = *(bf16x8*)&As[(wm + mi * 16 + l16) * 32 + quad * 8];
        #pragma unroll
        for (int ni = 0; ni < 4; ni++) {
            gf[ni] = *(bf16x8*)&Gs[(wn + ni * 16 + l16) * 32 + quad * 8];
            uf[ni] = *(bf16x8*)&Us[(wn + ni * 16 + l16) * 32 + quad * 8];
        }
        #pragma unroll
        for (int mi = 0; mi < 4; mi++)
            #pragma unroll
            for (int ni = 0; ni < 4; ni++) {
                ag[mi][ni] = __builtin_amdgcn_mfma_f32_16x16x32_bf16(af[mi], gf[ni], ag[mi][ni], 0, 0, 0);
                au[mi][ni] = __builtin_amdgcn_mfma_f32_16x16x32_bf16(af[mi], uf[ni], au[mi][ni], 0, 0, 0);
            }
        __syncthreads();
    }
    #pragma unroll
    for (int mi = 0; mi < 4; mi++)
        #pragma unroll
        for (int ni = 0; ni < 4; ni++)
            #pragma unroll
            for (int r = 0; r < 4; r++) {
                int row = m0 + wm + mi * 16 + quad * 4 + r;
                int col = n0 + wn + ni * 16 + l16;
                F[(size_t)row * N + col] = f2b(silu_f(ag[mi][ni][r]) * au[mi][ni][r]);
            }
}

// ------------------------------------- gk = g*k in-place, c = sum gk*k ------
__global__ __launch_bounds__(256) void gkc_k(
    const short* __restrict__ G, short* KG,
    float* __restrict__ Cj)
{
    const int bt  = blockIdx.x;
    const int tid = threadIdx.x;
    const int h = tid >> 4, d0 = (tid & 15) * 4;
    const size_t base = (size_t)bt * (HH * DH) + h * DH + d0;
    short4 gv = *(const short4*)(G + base);
    short4 kv = *(const short4*)(KG + base);
    float g0 = b2f(gv.x), g1 = b2f(gv.y), g2 = b2f(gv.z), g3 = b2f(gv.w);
    float k0 = b2f(kv.x), k1 = b2f(kv.y), k2 = b2f(kv.z), k3 = b2f(kv.w);
    float p0 = g0*k0, p1 = g1*k1, p2 = g2*k2, p3 = g3*k3;
    short4 ov; ov.x = f2b(p0); ov.y = f2b(p1); ov.z = f2b(p2); ov.w = f2b(p3);
    *(short4*)(KG + base) = ov;
    float cc = p0*k0 + p1*k1 + p2*k2 + p3*k3;
    #pragma unroll
    for (int m = 1; m < 16; m <<= 1) cc += __shfl_xor(cc, m);
    if ((tid & 15) == 0) {
        int b = bt >> 10, t = bt & (TT - 1);
        Cj[((size_t)b * HH + h) * TT + t] = cc;
    }
}

// -------------------------------------------------- flash geodesic attention -
__global__ __launch_bounds__(256) void attn_k(
    const short* __restrict__ Q, const short* __restrict__ G,
    const short* __restrict__ GK, const short* __restrict__ V,
    const float* __restrict__ Cj, short* __restrict__ O)
{
    __shared__ __align__(16) short Gs[64][72];
    __shared__ __align__(16) short GKs[64][72];
    __shared__ __align__(16) short Vt[64][72];
    __shared__ __align__(16) float Cs[64];
    __shared__ __align__(16) short Ps[4][16][72];

    const int pair = blockIdx.x;          // 0..7
    const int bh = blockIdx.y;
    const int b = bh >> 4, h = bh & 15;
    const int tid  = threadIdx.x;
    const int wave = tid >> 6, lane = tid & 63;
    const int l16  = lane & 15, quad = lane >> 4;

    const size_t bh_base = ((size_t)b * TT) * (HH * DH) + (size_t)h * DH;
    const float* cj_row = Cj + ((size_t)b * HH + h) * TT;

    const int sr2 = tid >> 3, sc2 = (tid & 7) * 8;
    const f32x4 z = {0.f, 0.f, 0.f, 0.f};

    for (int halfsel = 0; halfsel < 2; halfsel++) {
        const int it = halfsel ? 15 - pair : pair;
        const int i0 = it * 64;

        const int qrow = i0 + wave * 16 + l16;
        bf16x8 qf[2], qqf[2];
        #pragma unroll
        for (int kc = 0; kc < 2; kc++) {
            qf[kc] = *(const bf16x8*)(Q + bh_base + (size_t)qrow * (HH * DH) + kc * 32 + quad * 8);
            #pragma unroll
            for (int j = 0; j < 8; j++) {
                float f = b2f(qf[kc][j]);
                qqf[kc][j] = f2b(f * f);
            }
        }

        float m_i[4], l_i[4];
        f32x4 o_acc[4] = {z, z, z, z};
        #pragma unroll
        for (int r = 0; r < 4; r++) { m_i[r] = NEG_BIG; l_i[r] = 0.f; }

        for (int jt = 0; jt <= it; jt++) {
            const int j0 = jt * 64;
            #pragma unroll
            for (int pass = 0; pass < 2; pass++) {
                int jr = sr2 + pass * 32;
                size_t rb = bh_base + (size_t)(j0 + jr) * (HH * DH) + sc2;
                *(int4*)&Gs[jr][sc2]  = *(const int4*)(G + rb);
                *(int4*)&GKs[jr][sc2] = *(const int4*)(GK + rb);
                int4 vvec = *(const int4*)(V + rb);
                const short* vv = (const short*)&vvec;
                #pragma unroll
                for (int jj = 0; jj < 8; jj++) Vt[sc2 + jj][jr] = vv[jj];
            }
            if (tid < 64) Cs[tid] = cj_row[j0 + tid];
            __syncthreads();

            f32x4 s1[4] = {z, z, z, z}, s2[4] = {z, z, z, z};
            #pragma unroll
            for (int ns = 0; ns < 4; ns++) {
                #pragma unroll
                for (int kc = 0; kc < 2; kc++) {
                    bf16x8 gf  = *(bf16x8*)&Gs [ns * 16 + l16][kc * 32 + quad * 8];
                    bf16x8 gkf = *(bf16x8*)&GKs[ns * 16 + l16][kc * 32 + quad * 8];
                    s1[ns] = __builtin_amdgcn_mfma_f32_16x16x32_bf16(qqf[kc], gf,  s1[ns], 0, 0, 0);
                    s2[ns] = __builtin_amdgcn_mfma_f32_16x16x32_bf16(qf[kc],  gkf, s2[ns], 0, 0, 0);
                }
            }

            float p[4][4];
            #pragma unroll
            for (int ns = 0; ns < 4; ns++) {
                float cjv = Cs[ns * 16 + l16];
                #pragma unroll
                for (int r = 0; r < 4; r++)
                    p[ns][r] = (2.f * s2[ns][r] - s1[ns][r] - cjv) * 0.125f;
            }
            if (jt == it) {
                #pragma unroll
                for (int ns = 0; ns < 4; ns++) {
                    int j = j0 + ns * 16 + l16;
                    #pragma unroll
                    for (int r = 0; r < 4; r++) {
                        int i = i0 + wave * 16 + quad * 4 + r;
                        if (j > i) p[ns][r] = NEG_BIG;
                    }
                }
            }

            #pragma unroll
            for (int r = 0; r < 4; r++) {
                float mx = fmaxf(fmaxf(p[0][r], p[1][r]), fmaxf(p[2][r], p[3][r]));
                #pragma unroll
                for (int d2 = 1; d2 < 16; d2 <<= 1) mx = fmaxf(mx, __shfl_xor(mx, d2));
                float mnew = fmaxf(m_i[r], mx);
                float corr = __expf(m_i[r] - mnew);
                float sp = 0.f;
                #pragma unroll
                for (int ns = 0; ns < 4; ns++) {
                    float e = __expf(p[ns][r] - mnew);
                    p[ns][r] = e; sp += e;
                }
                #pragma unroll
                for (int d2 = 1; d2 < 16; d2 <<= 1) sp += __shfl_xor(sp, d2);
                l_i[r] = l_i[r] * corr + sp;
                m_i[r] = mnew;
                #pragma unroll
                for (int nv = 0; nv < 4; nv++) o_acc[nv][r] *= corr;
            }

            #pragma unroll
            for (int ns = 0; ns < 4; ns++)
                #pragma unroll
                for (int r = 0; r < 4; r++)
                    Ps[wave][quad * 4 + r][ns * 16 + l16] = f2b(p[ns][r]);

            bf16x8 pf[2];
            pf[0] = *(bf16x8*)&Ps[wave][l16][quad * 8];
            pf[1] = *(bf16x8*)&Ps[wave][l16][32 + quad * 8];
            #pragma unroll
            for (int nv = 0; nv < 4; nv++) {
                #pragma unroll
                for (int kc = 0; kc < 2; kc++) {
                    bf16x8 vf = *(bf16x8*)&Vt[nv * 16 + l16][kc * 32 + quad * 8];
                    o_acc[nv] = __builtin_amdgcn_mfma_f32_16x16x32_bf16(pf[kc], vf, o_acc[nv], 0, 0, 0);
                }
            }
            __syncthreads();
        }

        #pragma unroll
        for (int nv = 0; nv < 4; nv++) {
            #pragma unroll
            for (int r = 0; r < 4; r++) {
                int i = i0 + wave * 16 + quad * 4 + r;
                int d = nv * 16 + l16;
                O[bh_base + (size_t)i * (HH * DH) + d] = f2b(o_acc[nv][r] / l_i[r]);
            }
        }
    }
}

// ------------------------------------------------------------------ launch ---
extern "C" void kernel_launch(void* const* d_in, const int* in_sizes, int n_in,
                              void* d_out, int out_size, void* d_ws, size_t ws_size,
                              hipStream_t stream)
{
    const float* x   = (const float*)d_in[0];
    const float* n1w = (const float*)d_in[1];
    const float* n2w = (const float*)d_in[2];
    const float* wq  = (const float*)d_in[3];
    const float* wk  = (const float*)d_in[4];
    const float* wv  = (const float*)d_in[5];
    const float* wo  = (const float*)d_in[6];
    const float* mw1 = (const float*)d_in[7];
    const float* mw2 = (const float*)d_in[8];
    const float* gw  = (const float*)d_in[9];
    const float* uw  = (const float*)d_in[10];
    const float* dw  = (const float*)d_in[11];
    float* out = (float*)d_out;   // fp32; holds x2 = x + attn@wo after wo-phase

    // Arena (48 MB known-safe; F widens to 32 MB iff ws_size >= 64 MB):
    //  slot0: h -> g -> h2 | slot1: qb -> WgT | slot2: kb/gk -> WuT
    //  slot3: vb -> WdT    | slot4(32-40): WfT(6.8M) -> ob; F overlays 32..
    //  slot5(40-48): woT(2M)@40 | m1(2M)@42 | cj(.25M)@44 | mw2T(.5M)@44.5 -> F
    const size_t MB = 1u << 20;
    if (ws_size < 48 * MB) return;
    const bool bigF = (ws_size >= 64 * MB);
    char* wsb = (char*)d_ws;
    short* h    = (short*)(wsb);
    short* g    = (short*)(wsb);
    short* h2   = (short*)(wsb);
    short* qb   = (short*)(wsb + 8 * MB);
    short* WgT  = (short*)(wsb + 8 * MB);
    short* kb   = (short*)(wsb + 16 * MB);
    short* WuT  = (short*)(wsb + 16 * MB);
    short* vb   = (short*)(wsb + 24 * MB);
    short* WdT  = (short*)(wsb + 24 * MB);
    short* WfT  = (short*)(wsb + 32 * MB);   // 3328x1024 bf16 = 6.8 MB
    short* ob   = (short*)(wsb + 32 * MB);
    short* F    = (short*)(wsb + 32 * MB);   // 16 MB (32 MB if bigF)
    short* woT  = (short*)(wsb + 40 * MB);
    short* m1   = (short*)(wsb + 42 * MB);
    float* cj   = (float*)(wsb + 44 * MB);
    short* mw2T = (short*)(wsb + 44 * MB + 512 * 1024);

    const int M = BB * TT;  // 4096 token rows

    // Packed QKV+mnet1 transposed weights + wo/mw2
    convT_k<<<dim3(DD / 32, DD / 32),  256, 0, stream>>>(wq,  WfT,               DD, DD);
    convT_k<<<dim3(DD / 32, DD / 32),  256, 0, stream>>>(wk,  WfT + 1024 * 1024, DD, DD);
    convT_k<<<dim3(DD / 32, DD / 32),  256, 0, stream>>>(wv,  WfT + 2048 * 1024, DD, DD);
    convT_k<<<dim3(MHH / 32, DD / 32), 256, 0, stream>>>(mw1, WfT + 3072 * 1024, DD, MHH);
    convT_k<<<dim3(DD / 32, DD / 32),  256, 0, stream>>>(wo,  woT,  DD, DD);
    convT_k<<<dim3(DD / 32, MHH / 32), 256, 0, stream>>>(mw2, mw2T, MHH, DD);

    rmsnorm_k<<<M, 256, 0, stream>>>(x, n1w, h);
    gemm128_qkvm_k<<<dim3(3328 / 128, M / 128), 256, 0, stream>>>(h, WfT, qb, kb, vb, m1);
    gemm128_k<EP_SOFTPLUS,false,false><<<dim3(DD / 128, M / 128), 256, 0, stream>>>(
        m1, mw2T, g, nullptr, DD, MHH, MHH, MHH);
    gkc_k<<<M, 256, 0, stream>>>(g, kb, cj);
    attn_k<<<dim3(8, BB * HH), 256, 0, stream>>>(qb, g, kb, vb, cj, ob);

    // out = x; out += ob @ wo  (split-K=2, fp32 atomic accumulate)
    hipMemcpyAsync(out, x, (size_t)M * DD * sizeof(float), hipMemcpyDeviceToDevice, stream);
    gemm128_atomic_k<<<dim3(DD / 128, M / 128, 2), 256, 0, stream>>>(
        ob, woT, out, DD, 512, DD, DD);

    rmsnorm_k<<<M, 256, 0, stream>>>(out, n2w, h2);

    convT_k<<<dim3(DFF / 32, DD / 32), 256, 0, stream>>>(gw, WgT, DD, DFF);
    convT_k<<<dim3(DFF / 32, DD / 32), 256, 0, stream>>>(uw, WuT, DD, DFF);
    convT_k<<<dim3(DD / 32, DFF / 32), 256, 0, stream>>>(dw, WdT, DFF, DD);

    if (bigF) {   // one full-width SwiGLU (1024 blocks) + split-K=4 down
        gemm128_swiglu_k<<<dim3(DFF / 128, M / 128), 256, 0, stream>>>(h2, WgT, WuT, F, DFF, DD, DD);
        gemm128_atomic_k<<<dim3(DD / 128, M / 128, 4), 256, 0, stream>>>(
            F, WdT, out, DD, 1024, DFF, DFF);
    } else {      // two 2048-col halves, each with split-K=2 down
        const int NH = DFF / 2;
        for (int half = 0; half < 2; half++) {
            gemm128_swiglu_k<<<dim3(NH / 128, M / 128), 256, 0, stream>>>(
                h2, WgT + (size_t)half * NH * DD, WuT + (size_t)half * NH * DD, F, NH, DD, DD);
            gemm128_atomic_k<<<dim3(DD / 128, M / 128, 2), 256, 0, stream>>>(
                F, WdT + (size_t)half * NH, out, DD, 1024, NH, DFF);
        }
    }
}

// Round 8
// 569.983 us; speedup vs baseline: 1.7698x; 1.0686x over previous
//
#include <hip/hip_runtime.h>
#include <hip/hip_bf16.h>
#include <math.h>

// Problem dims
#define BB  4
#define TT  1024
#define DD  1024
#define HH  16
#define DH  64
#define DFF 4096
#define MHH 256

typedef __attribute__((ext_vector_type(8))) short bf16x8;   // 8 bf16 = 4 VGPRs
typedef __attribute__((ext_vector_type(4))) float f32x4;
typedef unsigned int u32;

#define NEG_BIG (-1e9f)

__device__ __forceinline__ float b2f(short s) {
    union { unsigned int u; float f; } x;
    x.u = ((unsigned int)(unsigned short)s) << 16;
    return x.f;
}
__device__ __forceinline__ short f2b(float f) {
    union { float f; unsigned int u; } x; x.f = f;
    unsigned int r = x.u + 0x7fffu + ((x.u >> 16) & 1u);   // RNE
    return (short)(r >> 16);
}
__device__ __forceinline__ float silu_f(float x) { return x / (1.f + __expf(-x)); }

// async global->LDS, 16B per lane. LDS dest must be wave_base + lane*16.
__device__ __forceinline__ void gld16(const short* g, short* l) {
    __builtin_amdgcn_global_load_lds(
        (const __attribute__((address_space(1))) u32*)g,
        (__attribute__((address_space(3))) u32*)l, 16, 0, 0);
}

// BK=64 staging: two BK=32 planes per buffer (proven layout per plane).
// Buffer = short[2*4096]: plane c holds rows 0..127 x k-cols [c*32, c*32+32).
// ga0 covers rows 0..63 (srow=tid>>2), ga1 rows 64..127.
#define STAGE64(ga0, ga1, lds, kb)                                  \
    {                                                               \
        gld16((ga0) + (kb),      &(lds)[tid * 8]);                  \
        gld16((ga1) + (kb),      &(lds)[2048 + tid * 8]);           \
        gld16((ga0) + (kb) + 32, &(lds)[4096 + tid * 8]);           \
        gld16((ga1) + (kb) + 32, &(lds)[4096 + 2048 + tid * 8]);    \
    }

// ------------------------------------------- weight fp32 [K,N] -> bf16 [N,K]
__global__ __launch_bounds__(256) void convT_k(
    const float* __restrict__ W, short* __restrict__ Wt, int K, int N)
{
    __shared__ __align__(16) short Ts[32][36];
    const int k0 = blockIdx.y * 32, n0 = blockIdx.x * 32;
    const int r = threadIdx.x >> 3, c4 = (threadIdx.x & 7) * 4;
    float4 v = *(const float4*)(W + (size_t)(k0 + r) * N + n0 + c4);
    Ts[r][c4 + 0] = f2b(v.x); Ts[r][c4 + 1] = f2b(v.y);
    Ts[r][c4 + 2] = f2b(v.z); Ts[r][c4 + 3] = f2b(v.w);
    __syncthreads();
    short4 o;
    o.x = Ts[c4 + 0][r]; o.y = Ts[c4 + 1][r];
    o.z = Ts[c4 + 2][r]; o.w = Ts[c4 + 3][r];
    *(short4*)(Wt + (size_t)(n0 + r) * K + k0 + c4) = o;
}

// ---------------------------------------------------------------- RMSNorm ---
__global__ __launch_bounds__(256) void rmsnorm_k(
    const float* __restrict__ X, const float* __restrict__ W, short* __restrict__ O)
{
    const int row = blockIdx.x;
    const int tid = threadIdx.x;
    float4 xv = ((const float4*)(X + (size_t)row * DD))[tid];
    float f0 = xv.x, f1 = xv.y, f2 = xv.z, f3 = xv.w;
    float ss = f0*f0 + f1*f1 + f2*f2 + f3*f3;
    #pragma unroll
    for (int m = 1; m < 64; m <<= 1) ss += __shfl_xor(ss, m);
    __shared__ float red[4];
    if ((tid & 63) == 0) red[tid >> 6] = ss;
    __syncthreads();
    float tot = red[0] + red[1] + red[2] + red[3];
    float scale = rsqrtf(tot * (1.f / DD) + 1e-6f);
    float4 wv = ((const float4*)W)[tid];
    short4 ov;
    ov.x = f2b(f0 * scale * wv.x);
    ov.y = f2b(f1 * scale * wv.y);
    ov.z = f2b(f2 * scale * wv.z);
    ov.w = f2b(f3 * scale * wv.w);
    ((short4*)(O + (size_t)row * DD))[tid] = ov;
}

// --------------------------------------------- 128x128 MFMA GEMM, BK=64 -----
#define EP_NONE     0
#define EP_SILU     1
#define EP_SOFTPLUS 2
#define EP_RES      3

template<int EP, bool CF32, bool AUXF32>
__global__ __launch_bounds__(256) void gemm128_k(
    const short* __restrict__ A, const short* __restrict__ Bt,
    void* Cv, const void* auxv,
    int N, int K, int lda, int ldb)
{
    __shared__ __align__(16) short As[2 * 4096];   // 2 planes of 128x32
    __shared__ __align__(16) short Bs[2 * 4096];
    const int tid  = threadIdx.x;
    const int wave = tid >> 6, lane = tid & 63;
    const int l16  = lane & 15, quad = lane >> 4;
    const int m0 = blockIdx.y * 128, n0 = blockIdx.x * 128;
    const int wm = (wave & 1) * 64, wn = (wave >> 1) * 64;

    f32x4 acc[4][4];
    #pragma unroll
    for (int i = 0; i < 4; i++)
        #pragma unroll
        for (int j = 0; j < 4; j++) acc[i][j] = (f32x4){0.f, 0.f, 0.f, 0.f};

    const int srow = tid >> 2, scol = (tid & 3) * 8;
    const short* ga0 = A  + (size_t)(m0 + srow)      * lda + scol;
    const short* ga1 = A  + (size_t)(m0 + 64 + srow) * lda + scol;
    const short* gb0 = Bt + (size_t)(n0 + srow)      * ldb + scol;
    const short* gb1 = Bt + (size_t)(n0 + 64 + srow) * ldb + scol;

    for (int kb = 0; kb < K; kb += 64) {
        STAGE64(ga0, ga1, As, kb);
        STAGE64(gb0, gb1, Bs, kb);
        __syncthreads();
        #pragma unroll
        for (int kc = 0; kc < 2; kc++) {
            bf16x8 af[4], bf[4];
            #pragma unroll
            for (int mi = 0; mi < 4; mi++)
                af[mi] = *(bf16x8*)&As[kc * 4096 + (wm + mi * 16 + l16) * 32 + quad * 8];
            #pragma unroll
            for (int ni = 0; ni < 4; ni++)
                bf[ni] = *(bf16x8*)&Bs[kc * 4096 + (wn + ni * 16 + l16) * 32 + quad * 8];
            #pragma unroll
            for (int mi = 0; mi < 4; mi++)
                #pragma unroll
                for (int ni = 0; ni < 4; ni++)
                    acc[mi][ni] = __builtin_amdgcn_mfma_f32_16x16x32_bf16(af[mi], bf[ni], acc[mi][ni], 0, 0, 0);
        }
        __syncthreads();
    }
    #pragma unroll
    for (int mi = 0; mi < 4; mi++) {
        #pragma unroll
        for (int ni = 0; ni < 4; ni++) {
            #pragma unroll
            for (int r = 0; r < 4; r++) {
                int row = m0 + wm + mi * 16 + quad * 4 + r;
                int col = n0 + wn + ni * 16 + l16;
                size_t idx = (size_t)row * N + col;
                float v = acc[mi][ni][r];
                if (EP == EP_SILU)          v = silu_f(v);
                else if (EP == EP_SOFTPLUS) v = fmaxf(v, 0.f) + log1pf(__expf(-fabsf(v)));
                else if (EP == EP_RES) {
                    if (AUXF32) v += ((const float*)auxv)[idx];
                    else        v += b2f(((const short*)auxv)[idx]);
                }
                if (CF32) ((float*)Cv)[idx] = v;
                else      ((short*)Cv)[idx] = f2b(v);
            }
        }
    }
}

// ------------- split-K 128x128 GEMM BK=64, fp32 atomic accumulate into out --
__global__ __launch_bounds__(256) void gemm128_atomic_k(
    const short* __restrict__ A, const short* __restrict__ Bt,
    float* out, int N, int Kc, int lda, int ldb)
{
    __shared__ __align__(16) short As[2 * 4096];
    __shared__ __align__(16) short Bs[2 * 4096];
    const int tid  = threadIdx.x;
    const int wave = tid >> 6, lane = tid & 63;
    const int l16  = lane & 15, quad = lane >> 4;
    const int m0 = blockIdx.y * 128, n0 = blockIdx.x * 128;
    const int wm = (wave & 1) * 64, wn = (wave >> 1) * 64;
    const int koff = blockIdx.z * Kc;

    f32x4 acc[4][4];
    #pragma unroll
    for (int i = 0; i < 4; i++)
        #pragma unroll
        for (int j = 0; j < 4; j++) acc[i][j] = (f32x4){0.f, 0.f, 0.f, 0.f};

    const int srow = tid >> 2, scol = (tid & 3) * 8;
    const short* ga0 = A  + (size_t)(m0 + srow)      * lda + koff + scol;
    const short* ga1 = A  + (size_t)(m0 + 64 + srow) * lda + koff + scol;
    const short* gb0 = Bt + (size_t)(n0 + srow)      * ldb + koff + scol;
    const short* gb1 = Bt + (size_t)(n0 + 64 + srow) * ldb + koff + scol;

    for (int kb = 0; kb < Kc; kb += 64) {
        STAGE64(ga0, ga1, As, kb);
        STAGE64(gb0, gb1, Bs, kb);
        __syncthreads();
        #pragma unroll
        for (int kc = 0; kc < 2; kc++) {
            bf16x8 af[4], bf[4];
            #pragma unroll
            for (int mi = 0; mi < 4; mi++)
                af[mi] = *(bf16x8*)&As[kc * 4096 + (wm + mi * 16 + l16) * 32 + quad * 8];
            #pragma unroll
            for (int ni = 0; ni < 4; ni++)
                bf[ni] = *(bf16x8*)&Bs[kc * 4096 + (wn + ni * 16 + l16) * 32 + quad * 8];
            #pragma unroll
            for (int mi = 0; mi < 4; mi++)
                #pragma unroll
                for (int ni = 0; ni < 4; ni++)
                    acc[mi][ni] = __builtin_amdgcn_mfma_f32_16x16x32_bf16(af[mi], bf[ni], acc[mi][ni], 0, 0, 0);
        }
        __syncthreads();
    }
    #pragma unroll
    for (int mi = 0; mi < 4; mi++)
        #pragma unroll
        for (int ni = 0; ni < 4; ni++)
            #pragma unroll
            for (int r = 0; r < 4; r++) {
                int row = m0 + wm + mi * 16 + quad * 4 + r;
                int col = n0 + wn + ni * 16 + l16;
                atomicAdd(out + (size_t)row * N + col, acc[mi][ni][r]);
            }
}

// --------------- fused QKV+mnet1 GEMM: N=3328 packed weights, BK=64 ---------
// Wf rows: [0,1024)=wq^T, [1024,2048)=wk^T, [2048,3072)=wv^T, [3072,3328)=mw1^T
__global__ __launch_bounds__(256) void gemm128_qkvm_k(
    const short* __restrict__ A, const short* __restrict__ Wf,
    short* __restrict__ Qb, short* __restrict__ Kb, short* __restrict__ Vb,
    short* __restrict__ M1)
{
    __shared__ __align__(16) short As[2 * 4096];
    __shared__ __align__(16) short Bs[2 * 4096];
    const int tid  = threadIdx.x;
    const int wave = tid >> 6, lane = tid & 63;
    const int l16  = lane & 15, quad = lane >> 4;
    const int m0 = blockIdx.y * 128, n0 = blockIdx.x * 128;
    const int wm = (wave & 1) * 64, wn = (wave >> 1) * 64;
    const int K = DD;

    f32x4 acc[4][4];
    #pragma unroll
    for (int i = 0; i < 4; i++)
        #pragma unroll
        for (int j = 0; j < 4; j++) acc[i][j] = (f32x4){0.f, 0.f, 0.f, 0.f};

    const int srow = tid >> 2, scol = (tid & 3) * 8;
    const short* ga0 = A  + (size_t)(m0 + srow)      * K + scol;
    const short* ga1 = A  + (size_t)(m0 + 64 + srow) * K + scol;
    const short* gb0 = Wf + (size_t)(n0 + srow)      * K + scol;
    const short* gb1 = Wf + (size_t)(n0 + 64 + srow) * K + scol;

    for (int kb = 0; kb < K; kb += 64) {
        STAGE64(ga0, ga1, As, kb);
        STAGE64(gb0, gb1, Bs, kb);
        __syncthreads();
        #pragma unroll
        for (int kc = 0; kc < 2; kc++) {
            bf16x8 af[4], bf[4];
            #pragma unroll
            for (int mi = 0; mi < 4; mi++)
                af[mi] = *(bf16x8*)&As[kc * 4096 + (wm + mi * 16 + l16) * 32 + quad * 8];
            #pragma unroll
            for (int ni = 0; ni < 4; ni++)
                bf[ni] = *(bf16x8*)&Bs[kc * 4096 + (wn + ni * 16 + l16) * 32 + quad * 8];
            #pragma unroll
            for (int mi = 0; mi < 4; mi++)
                #pragma unroll
                for (int ni = 0; ni < 4; ni++)
                    acc[mi][ni] = __builtin_amdgcn_mfma_f32_16x16x32_bf16(af[mi], bf[ni], acc[mi][ni], 0, 0, 0);
        }
        __syncthreads();
    }
    short* dst; int base, ldc; bool dosilu = false;
    if      (n0 < 1024) { dst = Qb; base = 0;    ldc = 1024; }
    else if (n0 < 2048) { dst = Kb; base = 1024; ldc = 1024; }
    else if (n0 < 3072) { dst = Vb; base = 2048; ldc = 1024; }
    else                { dst = M1; base = 3072; ldc = 256; dosilu = true; }
    #pragma unroll
    for (int mi = 0; mi < 4; mi++)
        #pragma unroll
        for (int ni = 0; ni < 4; ni++)
            #pragma unroll
            for (int r = 0; r < 4; r++) {
                int row = m0 + wm + mi * 16 + quad * 4 + r;
                int col = n0 + wn + ni * 16 + l16 - base;
                float v = acc[mi][ni][r];
                if (dosilu) v = silu_f(v);
                dst[(size_t)row * ldc + col] = f2b(v);
            }
}

// ------------------------- 128x128 fused SwiGLU (gate & up) GEMM, BK=64 -----
__global__ __launch_bounds__(256) void gemm128_swiglu_k(
    const short* __restrict__ A, const short* __restrict__ Gt,
    const short* __restrict__ Ut, short* __restrict__ F,
    int N, int K, int ldb)
{
    __shared__ __align__(16) short As[2 * 4096];
    __shared__ __align__(16) short Gs[2 * 4096];
    __shared__ __align__(16) short Us[2 * 4096];
    const int tid  = threadIdx.x;
    const int wave = tid >> 6, lane = tid & 63;
    const int l16  = lane & 15, quad = lane >> 4;
    const int m0 = blockIdx.y * 128, n0 = blockIdx.x * 128;
    const int wm = (wave & 1) * 64, wn = (wave >> 1) * 64;

    f32x4 ag[4][4], au[4][4];
    #pragma unroll
    for (int i = 0; i < 4; i++)
        #pragma unroll
        for (int j = 0; j < 4; j++) {
            ag[i][j] = (f32x4){0.f, 0.f, 0.f, 0.f};
            au[i][j] = (f32x4){0.f, 0.f, 0.f, 0.f};
        }

    const int srow = tid >> 2, scol = (tid & 3) * 8;
    const short* ga0 = A  + (size_t)(m0 + srow)      * K   + scol;
    const short* ga1 = A  + (size_t)(m0 + 64 + srow) * K   + scol;
    const short* gg0 = Gt + (size_t)(n0 + srow)      * ldb + scol;
    const short* gg1 = Gt + (size_t)(n0 + 64 + srow) * ldb + scol;
    const short* gu0 = Ut + (size_t)(n0 + srow)      * ldb + scol;
    const short* gu1 = Ut + (size_t)(n0 + 64 + srow) * ldb + scol;

    for (int kb = 0; kb < K; kb += 64) {
        STAGE64(ga0, ga1, As, kb);
        STAGE64(gg0, gg1, Gs, kb);
        STAGE64(gu0, gu1, Us, kb);
        __syncthreads();
        #pragma unroll
        for (int kc = 0; kc < 2; kc++) {
            bf16x8 af[4], gf[4], uf[4];
            #pragma unroll
            for (int mi = 0; mi < 4; mi++)
                af[mi] = *(bf16x8*)&As[kc * 4096 + (wm + mi * 16 + l16) * 32 + quad * 8];
            #pragma unroll
            for (int ni = 0; ni < 4; ni++) {
                gf[ni] = *(bf16x8*)&Gs[kc * 4096 + (wn + ni * 16 + l16) * 32 + quad * 8];
                uf[ni] = *(bf16x8*)&Us[kc * 4096 + (wn + ni * 16 + l16) * 32 + quad * 8];
            }
            #pragma unroll
            for (int mi = 0; mi < 4; mi++)
                #pragma unroll
                for (int ni = 0; ni < 4; ni++) {
                    ag[mi][ni] = __builtin_amdgcn_mfma_f32_16x16x32_bf16(af[mi], gf[ni], ag[mi][ni], 0, 0, 0);
                    au[mi][ni] = __builtin_amdgcn_mfma_f32_16x16x32_bf16(af[mi], uf[ni], au[mi][ni], 0, 0, 0);
                }
        }
        __syncthreads();
    }
    #pragma unroll
    for (int mi = 0; mi < 4; mi++)
        #pragma unroll
        for (int ni = 0; ni < 4; ni++)
            #pragma unroll
            for (int r = 0; r < 4; r++) {
                int row = m0 + wm + mi * 16 + quad * 4 + r;
                int col = n0 + wn + ni * 16 + l16;
                F[(size_t)row * N + col] = f2b(silu_f(ag[mi][ni][r]) * au[mi][ni][r]);
            }
}

// ------------------------------------- gk = g*k in-place, c = sum gk*k ------
__global__ __launch_bounds__(256) void gkc_k(
    const short* __restrict__ G, short* KG,
    float* __restrict__ Cj)
{
    const int bt  = blockIdx.x;
    const int tid = threadIdx.x;
    const int h = tid >> 4, d0 = (tid & 15) * 4;
    const size_t base = (size_t)bt * (HH * DH) + h * DH + d0;
    short4 gv = *(const short4*)(G + base);
    short4 kv = *(const short4*)(KG + base);
    float g0 = b2f(gv.x), g1 = b2f(gv.y), g2 = b2f(gv.z), g3 = b2f(gv.w);
    float k0 = b2f(kv.x), k1 = b2f(kv.y), k2 = b2f(kv.z), k3 = b2f(kv.w);
    float p0 = g0*k0, p1 = g1*k1, p2 = g2*k2, p3 = g3*k3;
    short4 ov; ov.x = f2b(p0); ov.y = f2b(p1); ov.z = f2b(p2); ov.w = f2b(p3);
    *(short4*)(KG + base) = ov;
    float cc = p0*k0 + p1*k1 + p2*k2 + p3*k3;
    #pragma unroll
    for (int m = 1; m < 16; m <<= 1) cc += __shfl_xor(cc, m);
    if ((tid & 15) == 0) {
        int b = bt >> 10, t = bt & (TT - 1);
        Cj[((size_t)b * HH + h) * TT + t] = cc;
    }
}

// -------------------------------------------------- flash geodesic attention -
__global__ __launch_bounds__(256) void attn_k(
    const short* __restrict__ Q, const short* __restrict__ G,
    const short* __restrict__ GK, const short* __restrict__ V,
    const float* __restrict__ Cj, short* __restrict__ O)
{
    __shared__ __align__(16) short Gs[64][72];
    __shared__ __align__(16) short GKs[64][72];
    __shared__ __align__(16) short Vt[64][72];
    __shared__ __align__(16) float Cs[64];
    __shared__ __align__(16) short Ps[4][16][72];

    const int pair = blockIdx.x;          // 0..7
    const int bh = blockIdx.y;
    const int b = bh >> 4, h = bh & 15;
    const int tid  = threadIdx.x;
    const int wave = tid >> 6, lane = tid & 63;
    const int l16  = lane & 15, quad = lane >> 4;

    const size_t bh_base = ((size_t)b * TT) * (HH * DH) + (size_t)h * DH;
    const float* cj_row = Cj + ((size_t)b * HH + h) * TT;

    const int sr2 = tid >> 3, sc2 = (tid & 7) * 8;
    const f32x4 z = {0.f, 0.f, 0.f, 0.f};

    for (int halfsel = 0; halfsel < 2; halfsel++) {
        const int it = halfsel ? 15 - pair : pair;
        const int i0 = it * 64;

        const int qrow = i0 + wave * 16 + l16;
        bf16x8 qf[2], qqf[2];
        #pragma unroll
        for (int kc = 0; kc < 2; kc++) {
            qf[kc] = *(const bf16x8*)(Q + bh_base + (size_t)qrow * (HH * DH) + kc * 32 + quad * 8);
            #pragma unroll
            for (int j = 0; j < 8; j++) {
                float f = b2f(qf[kc][j]);
                qqf[kc][j] = f2b(f * f);
            }
        }

        float m_i[4], l_i[4];
        f32x4 o_acc[4] = {z, z, z, z};
        #pragma unroll
        for (int r = 0; r < 4; r++) { m_i[r] = NEG_BIG; l_i[r] = 0.f; }

        for (int jt = 0; jt <= it; jt++) {
            const int j0 = jt * 64;
            #pragma unroll
            for (int pass = 0; pass < 2; pass++) {
                int jr = sr2 + pass * 32;
                size_t rb = bh_base + (size_t)(j0 + jr) * (HH * DH) + sc2;
                *(int4*)&Gs[jr][sc2]  = *(const int4*)(G + rb);
                *(int4*)&GKs[jr][sc2] = *(const int4*)(GK + rb);
                int4 vvec = *(const int4*)(V + rb);
                const short* vv = (const short*)&vvec;
                #pragma unroll
                for (int jj = 0; jj < 8; jj++) Vt[sc2 + jj][jr] = vv[jj];
            }
            if (tid < 64) Cs[tid] = cj_row[j0 + tid];
            __syncthreads();

            f32x4 s1[4] = {z, z, z, z}, s2[4] = {z, z, z, z};
            #pragma unroll
            for (int ns = 0; ns < 4; ns++) {
                #pragma unroll
                for (int kc = 0; kc < 2; kc++) {
                    bf16x8 gf  = *(bf16x8*)&Gs [ns * 16 + l16][kc * 32 + quad * 8];
                    bf16x8 gkf = *(bf16x8*)&GKs[ns * 16 + l16][kc * 32 + quad * 8];
                    s1[ns] = __builtin_amdgcn_mfma_f32_16x16x32_bf16(qqf[kc], gf,  s1[ns], 0, 0, 0);
                    s2[ns] = __builtin_amdgcn_mfma_f32_16x16x32_bf16(qf[kc],  gkf, s2[ns], 0, 0, 0);
                }
            }

            float p[4][4];
            #pragma unroll
            for (int ns = 0; ns < 4; ns++) {
                float cjv = Cs[ns * 16 + l16];
                #pragma unroll
                for (int r = 0; r < 4; r++)
                    p[ns][r] = (2.f * s2[ns][r] - s1[ns][r] - cjv) * 0.125f;
            }
            if (jt == it) {
                #pragma unroll
                for (int ns = 0; ns < 4; ns++) {
                    int j = j0 + ns * 16 + l16;
                    #pragma unroll
                    for (int r = 0; r < 4; r++) {
                        int i = i0 + wave * 16 + quad * 4 + r;
                        if (j > i) p[ns][r] = NEG_BIG;
                    }
                }
            }

            #pragma unroll
            for (int r = 0; r < 4; r++) {
                float mx = fmaxf(fmaxf(p[0][r], p[1][r]), fmaxf(p[2][r], p[3][r]));
                #pragma unroll
                for (int d2 = 1; d2 < 16; d2 <<= 1) mx = fmaxf(mx, __shfl_xor(mx, d2));
                float mnew = fmaxf(m_i[r], mx);
                float corr = __expf(m_i[r] - mnew);
                float sp = 0.f;
                #pragma unroll
                for (int ns = 0; ns < 4; ns++) {
                    float e = __expf(p[ns][r] - mnew);
                    p[ns][r] = e; sp += e;
                }
                #pragma unroll
                for (int d2 = 1; d2 < 16; d2 <<= 1) sp += __shfl_xor(sp, d2);
                l_i[r] = l_i[r] * corr + sp;
                m_i[r] = mnew;
                #pragma unroll
                for (int nv = 0; nv < 4; nv++) o_acc[nv][r] *= corr;
            }

            #pragma unroll
            for (int ns = 0; ns < 4; ns++)
                #pragma unroll
                for (int r = 0; r < 4; r++)
                    Ps[wave][quad * 4 + r][ns * 16 + l16] = f2b(p[ns][r]);

            bf16x8 pf[2];
            pf[0] = *(bf16x8*)&Ps[wave][l16][quad * 8];
            pf[1] = *(bf16x8*)&Ps[wave][l16][32 + quad * 8];
            #pragma unroll
            for (int nv = 0; nv < 4; nv++) {
                #pragma unroll
                for (int kc = 0; kc < 2; kc++) {
                    bf16x8 vf = *(bf16x8*)&Vt[nv * 16 + l16][kc * 32 + quad * 8];
                    o_acc[nv] = __builtin_amdgcn_mfma_f32_16x16x32_bf16(pf[kc], vf, o_acc[nv], 0, 0, 0);
                }
            }
            __syncthreads();
        }

        #pragma unroll
        for (int nv = 0; nv < 4; nv++) {
            #pragma unroll
            for (int r = 0; r < 4; r++) {
                int i = i0 + wave * 16 + quad * 4 + r;
                int d = nv * 16 + l16;
                O[bh_base + (size_t)i * (HH * DH) + d] = f2b(o_acc[nv][r] / l_i[r]);
            }
        }
    }
}

// ------------------------------------------------------------------ launch ---
extern "C" void kernel_launch(void* const* d_in, const int* in_sizes, int n_in,
                              void* d_out, int out_size, void* d_ws, size_t ws_size,
                              hipStream_t stream)
{
    const float* x   = (const float*)d_in[0];
    const float* n1w = (const float*)d_in[1];
    const float* n2w = (const float*)d_in[2];
    const float* wq  = (const float*)d_in[3];
    const float* wk  = (const float*)d_in[4];
    const float* wv  = (const float*)d_in[5];
    const float* wo  = (const float*)d_in[6];
    const float* mw1 = (const float*)d_in[7];
    const float* mw2 = (const float*)d_in[8];
    const float* gw  = (const float*)d_in[9];
    const float* uw  = (const float*)d_in[10];
    const float* dw  = (const float*)d_in[11];
    float* out = (float*)d_out;   // fp32; holds x2 = x + attn@wo after wo-phase

    // Arena (48 MB known-safe; F widens to 32 MB iff ws_size >= 64 MB):
    //  slot0: h -> g -> h2 | slot1: qb -> WgT | slot2: kb/gk -> WuT
    //  slot3: vb -> WdT    | slot4(32-40): WfT(6.8M) -> ob; F overlays 32..
    //  slot5(40-48): woT(2M)@40 | m1(2M)@42 | cj(.25M)@44 | mw2T(.5M)@44.5 -> F
    const size_t MB = 1u << 20;
    if (ws_size < 48 * MB) return;
    const bool bigF = (ws_size >= 64 * MB);
    char* wsb = (char*)d_ws;
    short* h    = (short*)(wsb);
    short* g    = (short*)(wsb);
    short* h2   = (short*)(wsb);
    short* qb   = (short*)(wsb + 8 * MB);
    short* WgT  = (short*)(wsb + 8 * MB);
    short* kb   = (short*)(wsb + 16 * MB);
    short* WuT  = (short*)(wsb + 16 * MB);
    short* vb   = (short*)(wsb + 24 * MB);
    short* WdT  = (short*)(wsb + 24 * MB);
    short* WfT  = (short*)(wsb + 32 * MB);   // 3328x1024 bf16 = 6.8 MB
    short* ob   = (short*)(wsb + 32 * MB);
    short* F    = (short*)(wsb + 32 * MB);   // 16 MB (32 MB if bigF)
    short* woT  = (short*)(wsb + 40 * MB);
    short* m1   = (short*)(wsb + 42 * MB);
    float* cj   = (float*)(wsb + 44 * MB);
    short* mw2T = (short*)(wsb + 44 * MB + 512 * 1024);

    const int M = BB * TT;  // 4096 token rows

    convT_k<<<dim3(DD / 32, DD / 32),  256, 0, stream>>>(wq,  WfT,               DD, DD);
    convT_k<<<dim3(DD / 32, DD / 32),  256, 0, stream>>>(wk,  WfT + 1024 * 1024, DD, DD);
    convT_k<<<dim3(DD / 32, DD / 32),  256, 0, stream>>>(wv,  WfT + 2048 * 1024, DD, DD);
    convT_k<<<dim3(MHH / 32, DD / 32), 256, 0, stream>>>(mw1, WfT + 3072 * 1024, DD, MHH);
    convT_k<<<dim3(DD / 32, DD / 32),  256, 0, stream>>>(wo,  woT,  DD, DD);
    convT_k<<<dim3(DD / 32, MHH / 32), 256, 0, stream>>>(mw2, mw2T, MHH, DD);

    rmsnorm_k<<<M, 256, 0, stream>>>(x, n1w, h);
    gemm128_qkvm_k<<<dim3(3328 / 128, M / 128), 256, 0, stream>>>(h, WfT, qb, kb, vb, m1);
    gemm128_k<EP_SOFTPLUS,false,false><<<dim3(DD / 128, M / 128), 256, 0, stream>>>(
        m1, mw2T, g, nullptr, DD, MHH, MHH, MHH);
    gkc_k<<<M, 256, 0, stream>>>(g, kb, cj);
    attn_k<<<dim3(8, BB * HH), 256, 0, stream>>>(qb, g, kb, vb, cj, ob);

    // out = x; out += ob @ wo  (split-K=2, fp32 atomic accumulate)
    hipMemcpyAsync(out, x, (size_t)M * DD * sizeof(float), hipMemcpyDeviceToDevice, stream);
    gemm128_atomic_k<<<dim3(DD / 128, M / 128, 2), 256, 0, stream>>>(
        ob, woT, out, DD, 512, DD, DD);

    rmsnorm_k<<<M, 256, 0, stream>>>(out, n2w, h2);

    convT_k<<<dim3(DFF / 32, DD / 32), 256, 0, stream>>>(gw, WgT, DD, DFF);
    convT_k<<<dim3(DFF / 32, DD / 32), 256, 0, stream>>>(uw, WuT, DD, DFF);
    convT_k<<<dim3(DD / 32, DFF / 32), 256, 0, stream>>>(dw, WdT, DFF, DD);

    if (bigF) {   // one full-width SwiGLU (1024 blocks) + split-K=4 down
        gemm128_swiglu_k<<<dim3(DFF / 128, M / 128), 256, 0, stream>>>(h2, WgT, WuT, F, DFF, DD, DD);
        gemm128_atomic_k<<<dim3(DD / 128, M / 128, 4), 256, 0, stream>>>(
            F, WdT, out, DD, 1024, DFF, DFF);
    } else {      // two 2048-col halves, each with split-K=2 down
        const int NH = DFF / 2;
        for (int half = 0; half < 2; half++) {
            gemm128_swiglu_k<<<dim3(NH / 128, M / 128), 256, 0, stream>>>(
                h2, WgT + (size_t)half * NH * DD, WuT + (size_t)half * NH * DD, F, NH, DD, DD);
            gemm128_atomic_k<<<dim3(DD / 128, M / 128, 2), 256, 0, stream>>>(
                F, WdT + (size_t)half * NH, out, DD, 1024, NH, DFF);
        }
    }
}